// Round 5
// baseline (573.380 us; speedup 1.0000x reference)
//
#include <hip/hip_runtime.h>
#include <cstdint>
#include <cstddef>

#define BB 8
#define NN 2048
#define FD 256
#define KK 205      // int(2048*0.1)+1
#define CAP 96      // max nnz per adj row (mean ~41, P(>96) ~ 1e-15)
#define SELCAP 256  // max selected columns (nsel ~205; clamped if ever exceeded)

// ---------- fused: ELL sparsify of adj + row sums + dg + y[r] = x[r,:].W ----------
__global__ __launch_bounds__(256) void k_spy(const float* __restrict__ adj, const float* __restrict__ x,
                                             const float* __restrict__ W, int* __restrict__ ell_idx,
                                             float* __restrict__ ell_val, int* __restrict__ ell_cnt,
                                             float* __restrict__ dg, float* __restrict__ rowsum,
                                             float* __restrict__ y) {
  int r = blockIdx.x;  // b*NN + n
  const float* arow = adj + (size_t)r * NN;
  int t = threadIdx.x;
  float lv[8]; int li[8]; int lc = 0; float ls = 0.f;
#pragma unroll
  for (int j = 0; j < 8; ++j) {
    int m = t + j * 256;
    float v = arow[m];
    if (v != 0.f) { lv[lc] = v; li[lc] = m; ++lc; ls += v; }
  }
  __shared__ int cnts[256];
  __shared__ float ssum[256];
  cnts[t] = lc; ssum[t] = ls;
  __syncthreads();
  for (int off = 1; off < 256; off <<= 1) {   // inclusive scan
    int add = (t >= off) ? cnts[t - off] : 0;
    __syncthreads();
    cnts[t] += add;
    __syncthreads();
  }
  int start = cnts[t] - lc;
  size_t base = (size_t)r * CAP;
  for (int e = 0; e < lc; ++e) {
    int p = start + e;
    if (p < CAP) { ell_idx[base + p] = li[e]; ell_val[base + p] = lv[e]; }
  }
  for (int off = 128; off > 0; off >>= 1) {   // rowsum reduce
    if (t < off) ssum[t] += ssum[t + off];
    __syncthreads();
  }
  if (t == 0) {
    int tot = cnts[255]; if (tot > CAP) tot = CAP;
    ell_cnt[r] = tot;
    float rs = ssum[0];
    rowsum[r] = rs;
    dg[r] = 1.0f / sqrtf(1.0f + rs);  // A_hat row sum = 1 + adj row sum >= 1 (clip is a no-op)
  }
  // ---- y phase (reuse ssum; t0 already consumed ssum[0] before this barrier) ----
  __syncthreads();
  ssum[t] = x[(size_t)r * FD + t] * W[t];
  __syncthreads();
  for (int off = 128; off > 0; off >>= 1) {
    if (t < off) ssum[t] += ssum[t + off];
    __syncthreads();
  }
  if (t == 0) y[r] = ssum[0];
}

// ---------- alpha[b,n] = sigmoid((dg[n]*(sum_m A_hat[n,m]*dg[m]*y[m]) + b)^2) ----------
__global__ __launch_bounds__(256) void k_alpha(const int* __restrict__ ell_idx, const float* __restrict__ ell_val,
                                               const int* __restrict__ ell_cnt, const float* __restrict__ dg,
                                               const float* __restrict__ y, const float* __restrict__ bptr,
                                               float* __restrict__ alpha) {
  int lane = threadIdx.x & 63, wv = threadIdx.x >> 6;
  int r = blockIdx.x * 4 + wv;
  int b = r / NN;
  int cnt = ell_cnt[r];
  size_t base = (size_t)r * CAP;
  const float* dgb = dg + (size_t)b * NN;
  const float* yb = y + (size_t)b * NN;
  float acc = 0.f;
  for (int j = lane; j < cnt; j += 64) {
    int m = ell_idx[base + j];
    acc += ell_val[base + j] * dgb[m] * yb[m];
  }
#pragma unroll
  for (int off = 32; off > 0; off >>= 1) acc += __shfl_down(acc, off);
  if (lane == 0) {
    float dgn = dg[r];
    float z = dgn * (acc + dgn * y[r]) + bptr[0];  // identity (+1) diag term added explicitly
    float t2 = z * z;
    alpha[r] = 1.0f / (1.0f + expf(-t2));
  }
}

// ---------- rank-based exact top-K (ties -> smaller index first, like lax.top_k) ----------
// rank[i] = #{j: a_j > a_i} + #{j < i: a_j == a_i} is a strict total order; element with
// rank t is the t-th entry of lax.top_k. 8 blocks per batch, batch pinned to XCD via &7.
__global__ __launch_bounds__(256) void k_rank(const float* __restrict__ alpha, float* __restrict__ cutv,
                                              float* __restrict__ out_topi, int* __restrict__ sel_cnt) {
  __shared__ unsigned int keys[NN];  // 8 KiB: alpha bits (alpha >= 0.5 > 0 -> bit order == value order)
  int b = blockIdx.x & 7;
  int chunk = blockIdx.x >> 3;
  int t = threadIdx.x;
  if (chunk == 0 && t == 0) sel_cnt[b] = 0;   // replaces the sel_cnt memset dispatch
  const float* ab = alpha + (size_t)b * NN;
  for (int i = t; i < NN; i += 256) keys[i] = __float_as_uint(ab[i]);
  __syncthreads();
  int i = chunk * 256 + t;
  unsigned int ai = keys[i];
  int rank = 0;
  const uint4* k4 = (const uint4*)keys;       // broadcast reads: all lanes same addr, conflict-free
#pragma unroll 4
  for (int j4 = 0; j4 < NN / 4; ++j4) {
    uint4 v = k4[j4];
    int j = j4 * 4;
    rank += (v.x > ai) || (v.x == ai && (j + 0) < i);
    rank += (v.y > ai) || (v.y == ai && (j + 1) < i);
    rank += (v.z > ai) || (v.z == ai && (j + 2) < i);
    rank += (v.w > ai) || (v.w == ai && (j + 3) < i);
  }
  if (rank < KK) out_topi[(size_t)b * KK + rank] = (float)i;
  if (rank == KK - 1) cutv[b] = __uint_as_float(ai);
}

// ---------- cut_alpha + selected-column compaction ----------
__global__ __launch_bounds__(256) void k_selcut(const float* __restrict__ alpha, const float* __restrict__ cutv,
                                                float* __restrict__ cutA, int* __restrict__ selidx,
                                                int* __restrict__ sel_list, int* __restrict__ sel_cnt) {
  int r = blockIdx.x * 256 + threadIdx.x;
  int b = r / NN, n = r % NN;
  float ca = fmaxf(alpha[r] + 1e-7f - cutv[b], 0.0f);
  cutA[r] = ca;
  int s = -1;
  if (ca > 0.f) {
    s = atomicAdd(&sel_cnt[b], 1);
    if (s < SELCAP) sel_list[b * SELCAP + s] = n; else s = -1;
  }
  selidx[r] = s;
}

// ---------- fused: normalized S row -> dense output row + compact Sc row (no memsets needed) ----------
__global__ __launch_bounds__(256) void k_sbuild(const int* __restrict__ ell_idx, const float* __restrict__ ell_val,
                                                const int* __restrict__ ell_cnt, const float* __restrict__ dg,
                                                const float* __restrict__ rowsum, const float* __restrict__ cutA,
                                                const int* __restrict__ selidx, float* __restrict__ inv_eff,
                                                float* __restrict__ Sc, float* __restrict__ outS) {
  __shared__ float row[NN];        // 8 KiB dense S row
  __shared__ float scrow[SELCAP];  // 1 KiB compact row
  __shared__ int   sidx[CAP];
  __shared__ float sterm[CAP];
  __shared__ float red[256];
  __shared__ float s_inv, s_dv;
  int r = blockIdx.x;  // b*NN + n
  int b = r >> 11;
  int t = threadIdx.x;
#pragma unroll
  for (int j = 0; j < NN / 256; ++j) row[t + j * 256] = 0.f;
  if (t < SELCAP) scrow[t] = 0.f;
  int cnt = ell_cnt[r];
  size_t base = (size_t)r * CAP;
  float dgn = dg[r];
  const float* dgb = dg + (size_t)b * NN;
  const float* cab = cutA + (size_t)b * NN;
  const int* sib = selidx + (size_t)b * NN;
  float part = 0.f;
  for (int j = t; j < cnt; j += 256) {
    int m = ell_idx[base + j];
    float term = dgn * ell_val[base + j] * dgb[m] * cab[m];
    sidx[j] = m; sterm[j] = term;
    part += term;
  }
  red[t] = part;
  __syncthreads();
  for (int off = 128; off > 0; off >>= 1) {
    if (t < off) red[t] += red[t + off];
    __syncthreads();
  }
  if (t == 0) {
    float diag = dgn * dgn * cutA[r];                 // "+I" diag of A_hat, col n
    float rho = red[0] + diag;                         // L1 row sum (all terms >= 0)
    float inv = (rowsum[r] > 0.f) ? (1.0f / fmaxf(rho, 1e-12f)) : 0.f;  // mask * normalize
    s_inv = inv; s_dv = diag * inv;
    inv_eff[r] = inv;
  }
  __syncthreads();
  float inv = s_inv;
  for (int j = t; j < cnt; j += 256) {               // distinct m per j -> no conflicts
    float v = sterm[j] * inv;
    row[sidx[j]] = v;
    int si = sib[sidx[j]];
    if (si >= 0) scrow[si] = v;
  }
  __syncthreads();
  if (t == 0) {                                       // diag after barrier: safe vs self-loop overlap
    int n = r & (NN - 1);
    row[n] += s_dv;
    int si = sib[n];
    if (si >= 0) scrow[si] += s_dv;
  }
  __syncthreads();
  float4* dst = (float4*)(outS + (size_t)r * NN);
  const float4* src = (const float4*)row;
#pragma unroll
  for (int j = 0; j < NN / 4 / 256; ++j) dst[t + j * 256] = src[t + j * 256];
  if (t < SELCAP) Sc[(size_t)r * SELCAP + t] = scrow[t];
}

// ---------- M[n, :] = sum_k adj[n,k] * Sc[k, :]  (dense-compact; batch pinned to XCD) ----------
__global__ __launch_bounds__(256) void k_M(const int* __restrict__ ell_idx, const float* __restrict__ ell_val,
                                           const int* __restrict__ ell_cnt, const float* __restrict__ Sc,
                                           float* __restrict__ Mmat) {
  int b = blockIdx.x & 7;           // batch -> XCD: Sc[b] (2 MB) stays L2-resident
  int n = blockIdx.x >> 3;
  int r = b * NN + n;
  int t = threadIdx.x;
  __shared__ int srk[CAP];
  __shared__ float sav[CAP];
  int cnt = ell_cnt[r];
  size_t base = (size_t)r * CAP;
  for (int e = t; e < cnt; e += 256) {
    srk[e] = b * NN + ell_idx[base + e];
    sav[e] = ell_val[base + e];
  }
  __syncthreads();
  float a0 = 0.f;
  for (int e = 0; e < cnt; ++e) a0 += sav[e] * Sc[(size_t)srk[e] * SELCAP + t];
  Mmat[(size_t)r * SELCAP + t] = a0;
}

// ---------- fused epilogue per selected m: xc row + coarse row (XCD-swizzled) ----------
__global__ __launch_bounds__(256) void k_epi(const float* __restrict__ x, const int* __restrict__ ell_idx,
                                             const float* __restrict__ ell_val, const int* __restrict__ ell_cnt,
                                             const float* __restrict__ dg, const float* __restrict__ cutA,
                                             const float* __restrict__ inv_eff, const int* __restrict__ sel_list,
                                             const int* __restrict__ sel_cnt, const float* __restrict__ Mmat,
                                             float* __restrict__ xc, float* __restrict__ coarse) {
  int b = blockIdx.x & 7;           // batch -> XCD: x[b], Mmat[b] (2 MB each) stay L2-resident
  int i = blockIdx.x >> 3;
  int nsel = sel_cnt[b]; if (nsel > SELCAP) nsel = SELCAP;
  if (i >= nsel) return;
  int m = sel_list[b * SELCAP + i];
  int rm = b * NN + m;
  int cnt = ell_cnt[rm];
  size_t base = (size_t)rm * CAP;
  __shared__ int cn[CAP + 1];    // global row index of n
  __shared__ float cw[CAP + 1];  // S[n,m] (column m of S == row m of adj by symmetry, + diag)
  float dgm = dg[rm], cam = cutA[rm];
  for (int j = threadIdx.x; j <= cnt; j += 256) {
    if (j < cnt) {
      int n = ell_idx[base + j];
      cn[j] = b * NN + n;
      cw[j] = ell_val[base + j] * dg[b * NN + n] * dgm * cam * inv_eff[b * NN + n];
    } else {
      cn[j] = rm;
      cw[j] = dgm * dgm * cam * inv_eff[rm];
    }
  }
  __syncthreads();
  int t = threadIdx.x;
  float axc = 0.f, aco = 0.f;
  for (int e = 0; e <= cnt; ++e) {
    float w = cw[e];
    if (w == 0.f) continue;
    size_t rn = (size_t)cn[e];
    axc += w * x[rn * FD + t];
    aco += w * Mmat[rn * SELCAP + t];
  }
  xc[(size_t)rm * FD + t] = axc;
  if (t < nsel) {
    float* crow = coarse + (size_t)rm * NN;
    crow[sel_list[b * SELCAP + t]] = floorf(aco * 10000.0f) / 10000.0f;
  }
}

extern "C" void kernel_launch(void* const* d_in, const int* in_sizes, int n_in,
                              void* d_out, int out_size, void* d_ws, size_t ws_size,
                              hipStream_t stream) {
  (void)in_sizes; (void)n_in; (void)ws_size; (void)out_size;
  const float* x = (const float*)d_in[0];
  const float* adj = (const float*)d_in[1];
  const float* W = (const float*)d_in[2];
  const float* bptr = (const float*)d_in[3];

  float* out = (float*)d_out;
  const size_t XC_SZ = (size_t)BB * NN * FD;   // 4,194,304
  const size_t CO_SZ = (size_t)BB * NN * NN;   // 33,554,432
  const size_t S_SZ  = (size_t)BB * NN * NN;   // 33,554,432
  float* out_xc = out;
  float* out_co = out + XC_SZ;
  float* out_S  = out + XC_SZ + CO_SZ;
  float* out_ti = out + XC_SZ + CO_SZ + S_SZ;  // topi as float (written fully by k_rank)

  char* w = (char*)d_ws;
  int*   ell_idx = (int*)w;   w += (size_t)BB * NN * CAP * 4;
  float* ell_val = (float*)w; w += (size_t)BB * NN * CAP * 4;
  float* Sc      = (float*)w; w += (size_t)BB * NN * SELCAP * 4;
  float* Mmat    = (float*)w; w += (size_t)BB * NN * SELCAP * 4;
  int*   ell_cnt = (int*)w;   w += (size_t)BB * NN * 4;
  float* dg      = (float*)w; w += (size_t)BB * NN * 4;
  float* rowsum  = (float*)w; w += (size_t)BB * NN * 4;
  float* yv      = (float*)w; w += (size_t)BB * NN * 4;
  float* alpha   = (float*)w; w += (size_t)BB * NN * 4;
  float* cutA    = (float*)w; w += (size_t)BB * NN * 4;
  float* inv_eff = (float*)w; w += (size_t)BB * NN * 4;
  int*   selidx  = (int*)w;   w += (size_t)BB * NN * 4;
  float* cutv    = (float*)w; w += (size_t)BB * 4;
  int*   sel_cnt = (int*)w;   w += (size_t)BB * 4;
  int*   sel_list= (int*)w;   w += (size_t)BB * SELCAP * 4;

  // zero only xc+coarse (S/Sc fully written by k_sbuild; topi fully written by k_rank;
  // sel_cnt zeroed inside k_rank)
  hipMemsetAsync(out, 0, (XC_SZ + CO_SZ) * sizeof(float), stream);

  k_spy<<<BB * NN, 256, 0, stream>>>(adj, x, W, ell_idx, ell_val, ell_cnt, dg, rowsum, yv);
  k_alpha<<<BB * NN / 4, 256, 0, stream>>>(ell_idx, ell_val, ell_cnt, dg, yv, bptr, alpha);
  k_rank<<<BB * 8, 256, 0, stream>>>(alpha, cutv, out_ti, sel_cnt);
  k_selcut<<<BB * NN / 256, 256, 0, stream>>>(alpha, cutv, cutA, selidx, sel_list, sel_cnt);
  k_sbuild<<<BB * NN, 256, 0, stream>>>(ell_idx, ell_val, ell_cnt, dg, rowsum, cutA, selidx,
                                        inv_eff, Sc, out_S);
  k_M<<<BB * NN, 256, 0, stream>>>(ell_idx, ell_val, ell_cnt, Sc, Mmat);
  k_epi<<<BB * SELCAP, 256, 0, stream>>>(x, ell_idx, ell_val, ell_cnt, dg, cutA, inv_eff,
                                         sel_list, sel_cnt, Mmat, out_xc, out_co);
}

// Round 6
// 565.699 us; speedup vs baseline: 1.0136x; 1.0136x over previous
//
#include <hip/hip_runtime.h>
#include <cstdint>
#include <cstddef>

#define BB 8
#define NN 2048
#define FD 256
#define KK 205      // int(2048*0.1)+1
#define CAP 96      // max nnz per adj row (mean ~41, P(>96) ~ 1e-15)
#define SELCAP 256  // max selected columns (nsel ~205; clamped if ever exceeded)

// ---------- fused: ELL sparsify of adj (atomic compaction) + row sum + dg + y = x.W ----------
__global__ __launch_bounds__(256) void k_spy(const float* __restrict__ adj, const float* __restrict__ x,
                                             const float* __restrict__ W, int* __restrict__ ell_idx,
                                             float* __restrict__ ell_val, int* __restrict__ ell_cnt,
                                             float* __restrict__ dg, float* __restrict__ rowsum,
                                             float* __restrict__ y) {
  int r = blockIdx.x;  // b*NN + n
  const float* arow = adj + (size_t)r * NN;
  int t = threadIdx.x;
  int lane = t & 63, wv = t >> 6;
  __shared__ int counter;
  __shared__ float wsum[4], wy[4];
  if (t == 0) counter = 0;
  __syncthreads();
  float lv[8]; int li[8]; int lc = 0; float ls = 0.f;
#pragma unroll
  for (int j = 0; j < 8; ++j) {
    int m = t + j * 256;
    float v = arow[m];
    if (v != 0.f) { lv[lc] = v; li[lc] = m; ++lc; ls += v; }
  }
  size_t base = (size_t)r * CAP;
  if (lc > 0) {
    int start = atomicAdd(&counter, lc);
    for (int e = 0; e < lc; ++e) {
      int p = start + e;
      if (p < CAP) { ell_idx[base + p] = li[e]; ell_val[base + p] = lv[e]; }
    }
  }
#pragma unroll
  for (int off = 32; off > 0; off >>= 1) ls += __shfl_down(ls, off);
  if (lane == 0) wsum[wv] = ls;
  float xv = x[(size_t)r * FD + t] * W[t];
#pragma unroll
  for (int off = 32; off > 0; off >>= 1) xv += __shfl_down(xv, off);
  if (lane == 0) wy[wv] = xv;
  __syncthreads();
  if (t == 0) {
    int tot = counter; if (tot > CAP) tot = CAP;
    ell_cnt[r] = tot;
    float rs = wsum[0] + wsum[1] + wsum[2] + wsum[3];
    rowsum[r] = rs;
    dg[r] = 1.0f / sqrtf(1.0f + rs);  // A_hat row sum = 1 + adj row sum >= 1 (clip is a no-op)
    y[r] = wy[0] + wy[1] + wy[2] + wy[3];
  }
}

// ---------- alpha[b,n] = sigmoid((dg[n]*(sum_m A_hat[n,m]*dg[m]*y[m]) + b)^2) ----------
__global__ __launch_bounds__(256) void k_alpha(const int* __restrict__ ell_idx, const float* __restrict__ ell_val,
                                               const int* __restrict__ ell_cnt, const float* __restrict__ dg,
                                               const float* __restrict__ y, const float* __restrict__ bptr,
                                               float* __restrict__ alpha) {
  int lane = threadIdx.x & 63, wv = threadIdx.x >> 6;
  int r = blockIdx.x * 4 + wv;
  int b = r / NN;
  int cnt = ell_cnt[r];
  size_t base = (size_t)r * CAP;
  const float* dgb = dg + (size_t)b * NN;
  const float* yb = y + (size_t)b * NN;
  float acc = 0.f;
  for (int j = lane; j < cnt; j += 64) {
    int m = ell_idx[base + j];
    acc += ell_val[base + j] * dgb[m] * yb[m];
  }
#pragma unroll
  for (int off = 32; off > 0; off >>= 1) acc += __shfl_down(acc, off);
  if (lane == 0) {
    float dgn = dg[r];
    float z = dgn * (acc + dgn * y[r]) + bptr[0];  // identity (+1) diag term added explicitly
    float t2 = z * z;
    alpha[r] = 1.0f / (1.0f + expf(-t2));
  }
}

// ---------- rank-based exact top-K (ties -> smaller index first, like lax.top_k) ----------
__global__ __launch_bounds__(256) void k_rank(const float* __restrict__ alpha, float* __restrict__ cutv,
                                              float* __restrict__ out_topi, int* __restrict__ sel_cnt) {
  __shared__ unsigned int keys[NN];  // 8 KiB: alpha bits (alpha >= 0.5 > 0 -> bit order == value order)
  int b = blockIdx.x & 7;
  int chunk = blockIdx.x >> 3;
  int t = threadIdx.x;
  if (chunk == 0 && t == 0) sel_cnt[b] = 0;   // replaces the sel_cnt memset dispatch
  const float* ab = alpha + (size_t)b * NN;
  for (int i = t; i < NN; i += 256) keys[i] = __float_as_uint(ab[i]);
  __syncthreads();
  int i = chunk * 256 + t;
  unsigned int ai = keys[i];
  int rank = 0;
  const uint4* k4 = (const uint4*)keys;       // broadcast reads: all lanes same addr, conflict-free
#pragma unroll 4
  for (int j4 = 0; j4 < NN / 4; ++j4) {
    uint4 v = k4[j4];
    int j = j4 * 4;
    rank += (v.x > ai) || (v.x == ai && (j + 0) < i);
    rank += (v.y > ai) || (v.y == ai && (j + 1) < i);
    rank += (v.z > ai) || (v.z == ai && (j + 2) < i);
    rank += (v.w > ai) || (v.w == ai && (j + 3) < i);
  }
  if (rank < KK) out_topi[(size_t)b * KK + rank] = (float)i;
  if (rank == KK - 1) cutv[b] = __uint_as_float(ai);
}

// ---------- cut_alpha + selected-column compaction ----------
__global__ __launch_bounds__(256) void k_selcut(const float* __restrict__ alpha, const float* __restrict__ cutv,
                                                float* __restrict__ cutA, int* __restrict__ selidx,
                                                int* __restrict__ sel_list, int* __restrict__ sel_cnt) {
  int r = blockIdx.x * 256 + threadIdx.x;
  int b = r / NN, n = r % NN;
  float ca = fmaxf(alpha[r] + 1e-7f - cutv[b], 0.0f);
  cutA[r] = ca;
  int s = -1;
  if (ca > 0.f) {
    s = atomicAdd(&sel_cnt[b], 1);
    if (s < SELCAP) sel_list[b * SELCAP + s] = n; else s = -1;
  }
  selidx[r] = s;
}

// ---------- fused: normalized S row -> dense output row + compact Sc row ----------
__global__ __launch_bounds__(256) void k_sbuild(const int* __restrict__ ell_idx, const float* __restrict__ ell_val,
                                                const int* __restrict__ ell_cnt, const float* __restrict__ dg,
                                                const float* __restrict__ rowsum, const float* __restrict__ cutA,
                                                const int* __restrict__ selidx, float* __restrict__ inv_eff,
                                                float* __restrict__ Sc, float* __restrict__ outS) {
  __shared__ float row[NN];        // 8 KiB dense S row
  __shared__ float scrow[SELCAP];  // 1 KiB compact row
  __shared__ int   sidx[CAP];
  __shared__ float sterm[CAP];
  __shared__ float wred[4];
  __shared__ float s_inv, s_dv;
  int r = blockIdx.x;  // b*NN + n
  int b = r >> 11;
  int t = threadIdx.x;
  int lane = t & 63, wv = t >> 6;
#pragma unroll
  for (int j = 0; j < NN / 256; ++j) row[t + j * 256] = 0.f;
  if (t < SELCAP) scrow[t] = 0.f;
  int cnt = ell_cnt[r];
  size_t base = (size_t)r * CAP;
  float dgn = dg[r];
  const float* dgb = dg + (size_t)b * NN;
  const float* cab = cutA + (size_t)b * NN;
  const int* sib = selidx + (size_t)b * NN;
  float part = 0.f;
  for (int j = t; j < cnt; j += 256) {
    int m = ell_idx[base + j];
    float term = dgn * ell_val[base + j] * dgb[m] * cab[m];
    sidx[j] = m; sterm[j] = term;
    part += term;
  }
#pragma unroll
  for (int off = 32; off > 0; off >>= 1) part += __shfl_down(part, off);
  if (lane == 0) wred[wv] = part;
  __syncthreads();
  if (t == 0) {
    float diag = dgn * dgn * cutA[r];                 // "+I" diag of A_hat, col n
    float rho = wred[0] + wred[1] + wred[2] + wred[3] + diag;  // L1 row sum (all >= 0)
    float inv = (rowsum[r] > 0.f) ? (1.0f / fmaxf(rho, 1e-12f)) : 0.f;  // mask * normalize
    s_inv = inv; s_dv = diag * inv;
    inv_eff[r] = inv;
  }
  __syncthreads();
  float inv = s_inv;
  for (int j = t; j < cnt; j += 256) {               // distinct m per j -> no conflicts
    float v = sterm[j] * inv;
    row[sidx[j]] = v;
    int si = sib[sidx[j]];
    if (si >= 0) scrow[si] = v;
  }
  __syncthreads();
  if (t == 0) {                                       // diag after barrier: safe vs self-loop overlap
    int n = r & (NN - 1);
    row[n] += s_dv;
    int si = sib[n];
    if (si >= 0) scrow[si] += s_dv;
  }
  __syncthreads();
  float4* dst = (float4*)(outS + (size_t)r * NN);
  const float4* src = (const float4*)row;
#pragma unroll
  for (int j = 0; j < NN / 4 / 256; ++j) dst[t + j * 256] = src[t + j * 256];
  if (t < SELCAP) Sc[(size_t)r * SELCAP + t] = scrow[t];
}

// ---------- M[n, :] = sum_k adj[n,k] * Sc[k, :]  (dense-compact; batch pinned to XCD) ----------
__global__ __launch_bounds__(256) void k_M(const int* __restrict__ ell_idx, const float* __restrict__ ell_val,
                                           const int* __restrict__ ell_cnt, const float* __restrict__ Sc,
                                           float* __restrict__ Mmat) {
  int b = blockIdx.x & 7;           // batch -> XCD: Sc[b] (2 MB) stays L2-resident
  int n = blockIdx.x >> 3;
  int r = b * NN + n;
  int t = threadIdx.x;
  __shared__ int srk[CAP];
  __shared__ float sav[CAP];
  int cnt = ell_cnt[r];
  size_t base = (size_t)r * CAP;
  for (int e = t; e < cnt; e += 256) {
    srk[e] = b * NN + ell_idx[base + e];
    sav[e] = ell_val[base + e];
  }
  __syncthreads();
  float a0 = 0.f;
  for (int e = 0; e < cnt; ++e) a0 += sav[e] * Sc[(size_t)srk[e] * SELCAP + t];
  Mmat[(size_t)r * SELCAP + t] = a0;
}

// ---------- full-grid epilogue: every row of xc and coarse written (no memset needed) ----------
__global__ __launch_bounds__(256) void k_epi2(const float* __restrict__ x, const int* __restrict__ ell_idx,
                                              const float* __restrict__ ell_val, const int* __restrict__ ell_cnt,
                                              const float* __restrict__ dg, const float* __restrict__ cutA,
                                              const float* __restrict__ inv_eff, const int* __restrict__ selidx,
                                              const int* __restrict__ sel_list, const int* __restrict__ sel_cnt,
                                              const float* __restrict__ Mmat,
                                              float* __restrict__ xc, float* __restrict__ coarse) {
  int b = blockIdx.x & 7;           // batch -> XCD: x[b], Mmat[b] (2 MB each) stay L2-resident
  int m = blockIdx.x >> 3;
  int rm = b * NN + m;
  int t = threadIdx.x;
  __shared__ float row[NN];         // 8 KiB coarse row
  __shared__ int cn[CAP + 1];
  __shared__ float cw[CAP + 1];
#pragma unroll
  for (int j = 0; j < NN / 256; ++j) row[t + j * 256] = 0.f;
  bool sel = selidx[rm] >= 0;       // block-uniform
  int nsel = sel_cnt[b]; if (nsel > SELCAP) nsel = SELCAP;
  int cnt = ell_cnt[rm];
  if (sel) {
    float dgm = dg[rm], cam = cutA[rm];
    // column m of S == row m of adj (exact symmetry) plus the diagonal (+1) entry
    for (int j = t; j <= cnt; j += 256) {
      if (j < cnt) {
        int n = ell_idx[(size_t)rm * CAP + j];
        cn[j] = b * NN + n;
        cw[j] = ell_val[(size_t)rm * CAP + j] * dg[b * NN + n] * dgm * cam * inv_eff[b * NN + n];
      } else {
        cn[j] = rm;
        cw[j] = dgm * dgm * cam * inv_eff[rm];
      }
    }
  }
  __syncthreads();
  float axc = 0.f;
  if (sel) {
    float aco = 0.f;
    for (int e = 0; e <= cnt; ++e) {
      float w = cw[e];
      if (w == 0.f) continue;
      size_t rn = (size_t)cn[e];
      axc += w * x[rn * FD + t];
      aco += w * Mmat[rn * SELCAP + t];
    }
    if (t < nsel) row[sel_list[b * SELCAP + t]] = floorf(aco * 10000.0f) / 10000.0f;
  }
  xc[(size_t)rm * FD + t] = axc;
  __syncthreads();
  float4* dst = (float4*)(coarse + (size_t)rm * NN);
  const float4* src = (const float4*)row;
#pragma unroll
  for (int j = 0; j < NN / 4 / 256; ++j) dst[t + j * 256] = src[t + j * 256];
}

extern "C" void kernel_launch(void* const* d_in, const int* in_sizes, int n_in,
                              void* d_out, int out_size, void* d_ws, size_t ws_size,
                              hipStream_t stream) {
  (void)in_sizes; (void)n_in; (void)ws_size; (void)out_size;
  const float* x = (const float*)d_in[0];
  const float* adj = (const float*)d_in[1];
  const float* W = (const float*)d_in[2];
  const float* bptr = (const float*)d_in[3];

  float* out = (float*)d_out;
  const size_t XC_SZ = (size_t)BB * NN * FD;   // 4,194,304
  const size_t CO_SZ = (size_t)BB * NN * NN;   // 33,554,432
  const size_t S_SZ  = (size_t)BB * NN * NN;   // 33,554,432
  float* out_xc = out;
  float* out_co = out + XC_SZ;
  float* out_S  = out + XC_SZ + CO_SZ;
  float* out_ti = out + XC_SZ + CO_SZ + S_SZ;  // topi as float (written fully by k_rank)

  char* w = (char*)d_ws;
  int*   ell_idx = (int*)w;   w += (size_t)BB * NN * CAP * 4;
  float* ell_val = (float*)w; w += (size_t)BB * NN * CAP * 4;
  float* Sc      = (float*)w; w += (size_t)BB * NN * SELCAP * 4;
  float* Mmat    = (float*)w; w += (size_t)BB * NN * SELCAP * 4;
  int*   ell_cnt = (int*)w;   w += (size_t)BB * NN * 4;
  float* dg      = (float*)w; w += (size_t)BB * NN * 4;
  float* rowsum  = (float*)w; w += (size_t)BB * NN * 4;
  float* yv      = (float*)w; w += (size_t)BB * NN * 4;
  float* alpha   = (float*)w; w += (size_t)BB * NN * 4;
  float* cutA    = (float*)w; w += (size_t)BB * NN * 4;
  float* inv_eff = (float*)w; w += (size_t)BB * NN * 4;
  int*   selidx  = (int*)w;   w += (size_t)BB * NN * 4;
  float* cutv    = (float*)w; w += (size_t)BB * 4;
  int*   sel_cnt = (int*)w;   w += (size_t)BB * 4;
  int*   sel_list= (int*)w;   w += (size_t)BB * SELCAP * 4;

  // every output byte written by kernels: xc+coarse by k_epi2, S by k_sbuild, topi by k_rank
  k_spy<<<BB * NN, 256, 0, stream>>>(adj, x, W, ell_idx, ell_val, ell_cnt, dg, rowsum, yv);
  k_alpha<<<BB * NN / 4, 256, 0, stream>>>(ell_idx, ell_val, ell_cnt, dg, yv, bptr, alpha);
  k_rank<<<BB * 8, 256, 0, stream>>>(alpha, cutv, out_ti, sel_cnt);
  k_selcut<<<BB * NN / 256, 256, 0, stream>>>(alpha, cutv, cutA, selidx, sel_list, sel_cnt);
  k_sbuild<<<BB * NN, 256, 0, stream>>>(ell_idx, ell_val, ell_cnt, dg, rowsum, cutA, selidx,
                                        inv_eff, Sc, out_S);
  k_M<<<BB * NN, 256, 0, stream>>>(ell_idx, ell_val, ell_cnt, Sc, Mmat);
  k_epi2<<<BB * NN, 256, 0, stream>>>(x, ell_idx, ell_val, ell_cnt, dg, cutA, inv_eff,
                                      selidx, sel_list, sel_cnt, Mmat, out_xc, out_co);
}

// Round 7
// 544.373 us; speedup vs baseline: 1.0533x; 1.0392x over previous
//
#include <hip/hip_runtime.h>
#include <cstdint>
#include <cstddef>

#define BB 8
#define NN 2048
#define FD 256
#define KK 205      // int(2048*0.1)+1
#define CAP 96      // max nnz per adj row (mean ~41, P(>96) ~ 1e-15)
#define SELCAP 256  // max selected columns (nsel ~205; clamped if ever exceeded)

// ---------- fused: ELL sparsify of adj (direct slot reservation, NO private arrays)
//            + row sum + dg + y = x.W ----------
__global__ __launch_bounds__(256) void k_spy(const float* __restrict__ adj, const float* __restrict__ x,
                                             const float* __restrict__ W, int* __restrict__ ell_idx,
                                             float* __restrict__ ell_val, int* __restrict__ ell_cnt,
                                             float* __restrict__ dg, float* __restrict__ y) {
  int r = blockIdx.x;  // b*NN + n
  const float4* arow4 = (const float4*)(adj + (size_t)r * NN);
  int t = threadIdx.x;
  int lane = t & 63, wv = t >> 6;
  __shared__ int counter;
  __shared__ float wsum[4], wy[4];
  if (t == 0) counter = 0;
  __syncthreads();
  size_t base = (size_t)r * CAP;
  float ls = 0.f;
#pragma unroll
  for (int j = 0; j < 2; ++j) {
    int i4 = t + j * 256;
    float4 v = arow4[i4];
    int m0 = i4 * 4;
    if (v.x != 0.f) { int p = atomicAdd(&counter, 1); if (p < CAP) { ell_idx[base + p] = m0 + 0; ell_val[base + p] = v.x; } ls += v.x; }
    if (v.y != 0.f) { int p = atomicAdd(&counter, 1); if (p < CAP) { ell_idx[base + p] = m0 + 1; ell_val[base + p] = v.y; } ls += v.y; }
    if (v.z != 0.f) { int p = atomicAdd(&counter, 1); if (p < CAP) { ell_idx[base + p] = m0 + 2; ell_val[base + p] = v.z; } ls += v.z; }
    if (v.w != 0.f) { int p = atomicAdd(&counter, 1); if (p < CAP) { ell_idx[base + p] = m0 + 3; ell_val[base + p] = v.w; } ls += v.w; }
  }
#pragma unroll
  for (int off = 32; off > 0; off >>= 1) ls += __shfl_down(ls, off);
  if (lane == 0) wsum[wv] = ls;
  float xv = x[(size_t)r * FD + t] * W[t];
#pragma unroll
  for (int off = 32; off > 0; off >>= 1) xv += __shfl_down(xv, off);
  if (lane == 0) wy[wv] = xv;
  __syncthreads();
  if (t == 0) {
    int tot = counter; if (tot > CAP) tot = CAP;
    ell_cnt[r] = tot;
    float rs = wsum[0] + wsum[1] + wsum[2] + wsum[3];
    dg[r] = 1.0f / sqrtf(1.0f + rs);  // A_hat row sum = 1 + adj row sum >= 1 (clip is a no-op)
    y[r] = wy[0] + wy[1] + wy[2] + wy[3];
  }
}

// ---------- alpha[b,n] = sigmoid((dg[n]*(sum_m A_hat[n,m]*dg[m]*y[m]) + b)^2) ----------
__global__ __launch_bounds__(256) void k_alpha(const int* __restrict__ ell_idx, const float* __restrict__ ell_val,
                                               const int* __restrict__ ell_cnt, const float* __restrict__ dg,
                                               const float* __restrict__ y, const float* __restrict__ bptr,
                                               float* __restrict__ alpha) {
  int lane = threadIdx.x & 63, wv = threadIdx.x >> 6;
  int r = blockIdx.x * 4 + wv;
  int b = r / NN;
  int cnt = ell_cnt[r];
  size_t base = (size_t)r * CAP;
  const float* dgb = dg + (size_t)b * NN;
  const float* yb = y + (size_t)b * NN;
  float acc = 0.f;
  for (int j = lane; j < cnt; j += 64) {
    int m = ell_idx[base + j];
    acc += ell_val[base + j] * dgb[m] * yb[m];
  }
#pragma unroll
  for (int off = 32; off > 0; off >>= 1) acc += __shfl_down(acc, off);
  if (lane == 0) {
    float dgn = dg[r];
    float z = dgn * (acc + dgn * y[r]) + bptr[0];  // identity (+1) diag term added explicitly
    float t2 = z * z;
    alpha[r] = 1.0f / (1.0f + expf(-t2));
  }
}

// ---------- rank-based exact top-K (ties -> smaller index first, like lax.top_k) ----------
__global__ __launch_bounds__(256) void k_rank(const float* __restrict__ alpha, float* __restrict__ cutv,
                                              float* __restrict__ out_topi, int* __restrict__ sel_cnt) {
  __shared__ unsigned int keys[NN];  // 8 KiB: alpha bits (alpha >= 0.5 > 0 -> bit order == value order)
  int b = blockIdx.x & 7;
  int chunk = blockIdx.x >> 3;
  int t = threadIdx.x;
  if (chunk == 0 && t == 0) sel_cnt[b] = 0;   // replaces the sel_cnt memset dispatch
  const float* ab = alpha + (size_t)b * NN;
  for (int i = t; i < NN; i += 256) keys[i] = __float_as_uint(ab[i]);
  __syncthreads();
  int i = chunk * 256 + t;
  unsigned int ai = keys[i];
  int rank = 0;
  const uint4* k4 = (const uint4*)keys;       // broadcast reads: all lanes same addr, conflict-free
#pragma unroll 4
  for (int j4 = 0; j4 < NN / 4; ++j4) {
    uint4 v = k4[j4];
    int j = j4 * 4;
    rank += (v.x > ai) || (v.x == ai && (j + 0) < i);
    rank += (v.y > ai) || (v.y == ai && (j + 1) < i);
    rank += (v.z > ai) || (v.z == ai && (j + 2) < i);
    rank += (v.w > ai) || (v.w == ai && (j + 3) < i);
  }
  if (rank < KK) out_topi[(size_t)b * KK + rank] = (float)i;
  if (rank == KK - 1) cutv[b] = __uint_as_float(ai);
}

// ---------- cut_alpha + selected-column compaction ----------
__global__ __launch_bounds__(256) void k_selcut(const float* __restrict__ alpha, const float* __restrict__ cutv,
                                                float* __restrict__ cutA, int* __restrict__ selidx,
                                                int* __restrict__ sel_list, int* __restrict__ sel_cnt) {
  int r = blockIdx.x * 256 + threadIdx.x;
  int b = r / NN, n = r % NN;
  float ca = fmaxf(alpha[r] + 1e-7f - cutv[b], 0.0f);
  cutA[r] = ca;
  int s = -1;
  if (ca > 0.f) {
    s = atomicAdd(&sel_cnt[b], 1);
    if (s < SELCAP) sel_list[b * SELCAP + s] = n; else s = -1;
  }
  selidx[r] = s;
}

// ---------- fused: normalized S row -> dense output row + compact Sc row ----------
__global__ __launch_bounds__(256) void k_sbuild(const int* __restrict__ ell_idx, const float* __restrict__ ell_val,
                                                const int* __restrict__ ell_cnt, const float* __restrict__ dg,
                                                const float* __restrict__ cutA, const int* __restrict__ selidx,
                                                float* __restrict__ inv_eff,
                                                float* __restrict__ Sc, float* __restrict__ outS) {
  __shared__ float row[NN];        // 8 KiB dense S row
  __shared__ float scrow[SELCAP];  // 1 KiB compact row
  __shared__ int   sidx[CAP];
  __shared__ float sterm[CAP];
  __shared__ float wred[4];
  __shared__ float s_inv, s_dv;
  int r = blockIdx.x;  // b*NN + n
  int b = r >> 11;
  int t = threadIdx.x;
  int lane = t & 63, wv = t >> 6;
#pragma unroll
  for (int j = 0; j < NN / 256; ++j) row[t + j * 256] = 0.f;
  if (t < SELCAP) scrow[t] = 0.f;
  int cnt = ell_cnt[r];
  size_t base = (size_t)r * CAP;
  float dgn = dg[r];
  const float* dgb = dg + (size_t)b * NN;
  const float* cab = cutA + (size_t)b * NN;
  const int* sib = selidx + (size_t)b * NN;
  float part = 0.f;
  for (int j = t; j < cnt; j += 256) {
    int m = ell_idx[base + j];
    float term = dgn * ell_val[base + j] * dgb[m] * cab[m];
    sidx[j] = m; sterm[j] = term;
    part += term;
  }
#pragma unroll
  for (int off = 32; off > 0; off >>= 1) part += __shfl_down(part, off);
  if (lane == 0) wred[wv] = part;
  __syncthreads();
  if (t == 0) {
    float diag = dgn * dgn * cutA[r];                 // "+I" diag of A_hat, col n
    float rho = wred[0] + wred[1] + wred[2] + wred[3] + diag;  // L1 row sum (all >= 0)
    float inv = (cnt > 0) ? (1.0f / fmaxf(rho, 1e-12f)) : 0.f;  // mask (adj rowsum>0 <=> cnt>0) * normalize
    s_inv = inv; s_dv = diag * inv;
    inv_eff[r] = inv;
  }
  __syncthreads();
  float inv = s_inv;
  for (int j = t; j < cnt; j += 256) {               // distinct m per j -> no conflicts
    float v = sterm[j] * inv;
    row[sidx[j]] = v;
    int si = sib[sidx[j]];
    if (si >= 0) scrow[si] = v;
  }
  __syncthreads();
  if (t == 0) {                                       // diag after barrier: safe vs self-loop overlap
    int n = r & (NN - 1);
    row[n] += s_dv;
    int si = sib[n];
    if (si >= 0) scrow[si] += s_dv;
  }
  __syncthreads();
  float4* dst = (float4*)(outS + (size_t)r * NN);
  const float4* src = (const float4*)row;
#pragma unroll
  for (int j = 0; j < NN / 4 / 256; ++j) dst[t + j * 256] = src[t + j * 256];
  if (t < SELCAP) Sc[(size_t)r * SELCAP + t] = scrow[t];
}

// ---------- M[n, :] = sum_k adj[n,k] * Sc[k, :]  (dense-compact; batch pinned to XCD) ----------
__global__ __launch_bounds__(256) void k_M(const int* __restrict__ ell_idx, const float* __restrict__ ell_val,
                                           const int* __restrict__ ell_cnt, const float* __restrict__ Sc,
                                           float* __restrict__ Mmat) {
  int b = blockIdx.x & 7;           // batch -> XCD: Sc[b] (2 MB) stays L2-resident
  int n = blockIdx.x >> 3;
  int r = b * NN + n;
  int t = threadIdx.x;
  __shared__ int srk[CAP];
  __shared__ float sav[CAP];
  int cnt = ell_cnt[r];
  size_t base = (size_t)r * CAP;
  for (int e = t; e < cnt; e += 256) {
    srk[e] = b * NN + ell_idx[base + e];
    sav[e] = ell_val[base + e];
  }
  __syncthreads();
  float a0 = 0.f;
  for (int e = 0; e < cnt; ++e) a0 += sav[e] * Sc[(size_t)srk[e] * SELCAP + t];
  Mmat[(size_t)r * SELCAP + t] = a0;
}

// ---------- full-grid epilogue: every row of xc and coarse written (no memset needed) ----------
__global__ __launch_bounds__(256) void k_epi2(const float* __restrict__ x, const int* __restrict__ ell_idx,
                                              const float* __restrict__ ell_val, const int* __restrict__ ell_cnt,
                                              const float* __restrict__ dg, const float* __restrict__ cutA,
                                              const float* __restrict__ inv_eff, const int* __restrict__ selidx,
                                              const int* __restrict__ sel_list, const int* __restrict__ sel_cnt,
                                              const float* __restrict__ Mmat,
                                              float* __restrict__ xc, float* __restrict__ coarse) {
  int b = blockIdx.x & 7;           // batch -> XCD: x[b], Mmat[b] (2 MB each) stay L2-resident
  int m = blockIdx.x >> 3;
  int rm = b * NN + m;
  int t = threadIdx.x;
  __shared__ float row[NN];         // 8 KiB coarse row
  __shared__ int cn[CAP + 1];
  __shared__ float cw[CAP + 1];
#pragma unroll
  for (int j = 0; j < NN / 256; ++j) row[t + j * 256] = 0.f;
  bool sel = selidx[rm] >= 0;       // block-uniform
  int nsel = sel_cnt[b]; if (nsel > SELCAP) nsel = SELCAP;
  int cnt = ell_cnt[rm];
  if (sel) {
    float dgm = dg[rm], cam = cutA[rm];
    // column m of S == row m of adj (exact symmetry) plus the diagonal (+1) entry
    for (int j = t; j <= cnt; j += 256) {
      if (j < cnt) {
        int n = ell_idx[(size_t)rm * CAP + j];
        cn[j] = b * NN + n;
        cw[j] = ell_val[(size_t)rm * CAP + j] * dg[b * NN + n] * dgm * cam * inv_eff[b * NN + n];
      } else {
        cn[j] = rm;
        cw[j] = dgm * dgm * cam * inv_eff[rm];
      }
    }
  }
  __syncthreads();
  float axc = 0.f;
  if (sel) {
    float aco = 0.f;
    for (int e = 0; e <= cnt; ++e) {
      float w = cw[e];
      if (w == 0.f) continue;
      size_t rn = (size_t)cn[e];
      axc += w * x[rn * FD + t];
      aco += w * Mmat[rn * SELCAP + t];
    }
    if (t < nsel) row[sel_list[b * SELCAP + t]] = floorf(aco * 10000.0f) / 10000.0f;
  }
  xc[(size_t)rm * FD + t] = axc;
  __syncthreads();
  float4* dst = (float4*)(coarse + (size_t)rm * NN);
  const float4* src = (const float4*)row;
#pragma unroll
  for (int j = 0; j < NN / 4 / 256; ++j) dst[t + j * 256] = src[t + j * 256];
}

extern "C" void kernel_launch(void* const* d_in, const int* in_sizes, int n_in,
                              void* d_out, int out_size, void* d_ws, size_t ws_size,
                              hipStream_t stream) {
  (void)in_sizes; (void)n_in; (void)ws_size; (void)out_size;
  const float* x = (const float*)d_in[0];
  const float* adj = (const float*)d_in[1];
  const float* W = (const float*)d_in[2];
  const float* bptr = (const float*)d_in[3];

  float* out = (float*)d_out;
  const size_t XC_SZ = (size_t)BB * NN * FD;   // 4,194,304
  const size_t CO_SZ = (size_t)BB * NN * NN;   // 33,554,432
  const size_t S_SZ  = (size_t)BB * NN * NN;   // 33,554,432
  float* out_xc = out;
  float* out_co = out + XC_SZ;
  float* out_S  = out + XC_SZ + CO_SZ;
  float* out_ti = out + XC_SZ + CO_SZ + S_SZ;  // topi as float (written fully by k_rank)

  char* w = (char*)d_ws;
  int*   ell_idx = (int*)w;   w += (size_t)BB * NN * CAP * 4;
  float* ell_val = (float*)w; w += (size_t)BB * NN * CAP * 4;
  float* Sc      = (float*)w; w += (size_t)BB * NN * SELCAP * 4;
  float* Mmat    = (float*)w; w += (size_t)BB * NN * SELCAP * 4;
  int*   ell_cnt = (int*)w;   w += (size_t)BB * NN * 4;
  float* dg      = (float*)w; w += (size_t)BB * NN * 4;
  float* yv      = (float*)w; w += (size_t)BB * NN * 4;
  float* alpha   = (float*)w; w += (size_t)BB * NN * 4;
  float* cutA    = (float*)w; w += (size_t)BB * NN * 4;
  float* inv_eff = (float*)w; w += (size_t)BB * NN * 4;
  int*   selidx  = (int*)w;   w += (size_t)BB * NN * 4;
  float* cutv    = (float*)w; w += (size_t)BB * 4;
  int*   sel_cnt = (int*)w;   w += (size_t)BB * 4;
  int*   sel_list= (int*)w;   w += (size_t)BB * SELCAP * 4;

  // every output byte written by kernels: xc+coarse by k_epi2, S by k_sbuild, topi by k_rank
  k_spy<<<BB * NN, 256, 0, stream>>>(adj, x, W, ell_idx, ell_val, ell_cnt, dg, yv);
  k_alpha<<<BB * NN / 4, 256, 0, stream>>>(ell_idx, ell_val, ell_cnt, dg, yv, bptr, alpha);
  k_rank<<<BB * 8, 256, 0, stream>>>(alpha, cutv, out_ti, sel_cnt);
  k_selcut<<<BB * NN / 256, 256, 0, stream>>>(alpha, cutv, cutA, selidx, sel_list, sel_cnt);
  k_sbuild<<<BB * NN, 256, 0, stream>>>(ell_idx, ell_val, ell_cnt, dg, cutA, selidx,
                                        inv_eff, Sc, out_S);
  k_M<<<BB * NN, 256, 0, stream>>>(ell_idx, ell_val, ell_cnt, Sc, Mmat);
  k_epi2<<<BB * NN, 256, 0, stream>>>(x, ell_idx, ell_val, ell_cnt, dg, cutA, inv_eff,
                                      selidx, sel_list, sel_cnt, Mmat, out_xc, out_co);
}

// Round 8
// 538.009 us; speedup vs baseline: 1.0657x; 1.0118x over previous
//
#include <hip/hip_runtime.h>
#include <cstdint>
#include <cstddef>

#define BB 8
#define NN 2048
#define FD 256
#define KK 205      // int(2048*0.1)+1
#define CAP 96      // max nnz per adj row (mean ~41, P(>96) ~ 1e-15)
#define SELCAP 256  // max selected columns (nsel ~205; clamped if ever exceeded)

// Packed ELL entry: x = column index, y = __float_as_int(value)

// ---------- fused: ELL sparsify of adj (ballot compaction) + row sum + dg + y = x.W ----------
__global__ __launch_bounds__(256) void k_spy(const float* __restrict__ adj, const float* __restrict__ x,
                                             const float* __restrict__ W, int2* __restrict__ ell,
                                             int* __restrict__ ell_cnt, float* __restrict__ dg,
                                             float* __restrict__ y) {
  int r = blockIdx.x;  // b*NN + n
  const float4* arow4 = (const float4*)(adj + (size_t)r * NN);
  int t = threadIdx.x;
  int lane = t & 63, wv = t >> 6;
  __shared__ int counter;
  __shared__ float wsum[4], wy[4];
  if (t == 0) counter = 0;
  __syncthreads();
  size_t base = (size_t)r * CAP;
  unsigned long long lmask = (1ull << lane) - 1;   // lane<=63 -> no UB
  float ls = 0.f;
#pragma unroll
  for (int j = 0; j < 2; ++j) {
    int i4 = t + j * 256;
    float4 v = arow4[i4];
    int m0 = i4 * 4;
    float vv[4] = {v.x, v.y, v.z, v.w};            // statically indexed below -> stays in VGPRs
#pragma unroll
    for (int c = 0; c < 4; ++c) {
      float val = vv[c];
      unsigned long long mk = __ballot(val != 0.f);
      if (mk) {
        int wbase = 0;
        if (lane == 0) wbase = atomicAdd(&counter, (int)__popcll(mk));
        wbase = __shfl(wbase, 0);                  // one atomic per wave per component
        if (val != 0.f) {
          int p = wbase + (int)__popcll(mk & lmask);
          if (p < CAP) ell[base + p] = make_int2(m0 + c, __float_as_int(val));
        }
      }
      ls += val;                                   // val==0 adds nothing
    }
  }
#pragma unroll
  for (int off = 32; off > 0; off >>= 1) ls += __shfl_down(ls, off);
  if (lane == 0) wsum[wv] = ls;
  float xv = x[(size_t)r * FD + t] * W[t];
#pragma unroll
  for (int off = 32; off > 0; off >>= 1) xv += __shfl_down(xv, off);
  if (lane == 0) wy[wv] = xv;
  __syncthreads();
  if (t == 0) {
    int tot = counter; if (tot > CAP) tot = CAP;
    ell_cnt[r] = tot;
    float rs = wsum[0] + wsum[1] + wsum[2] + wsum[3];
    dg[r] = 1.0f / sqrtf(1.0f + rs);  // A_hat row sum = 1 + adj row sum >= 1 (clip is a no-op)
    y[r] = wy[0] + wy[1] + wy[2] + wy[3];
  }
}

// ---------- alpha[b,n] = sigmoid((dg[n]*(sum_m A_hat[n,m]*dg[m]*y[m]) + b)^2) ----------
__global__ __launch_bounds__(256) void k_alpha(const int2* __restrict__ ell, const int* __restrict__ ell_cnt,
                                               const float* __restrict__ dg, const float* __restrict__ y,
                                               const float* __restrict__ bptr, float* __restrict__ alpha) {
  int lane = threadIdx.x & 63, wv = threadIdx.x >> 6;
  int r = blockIdx.x * 4 + wv;
  int b = r / NN;
  int cnt = ell_cnt[r];
  size_t base = (size_t)r * CAP;
  const float* dgb = dg + (size_t)b * NN;
  const float* yb = y + (size_t)b * NN;
  float acc = 0.f;
  for (int j = lane; j < cnt; j += 64) {
    int2 e = ell[base + j];
    acc += __int_as_float(e.y) * dgb[e.x] * yb[e.x];
  }
#pragma unroll
  for (int off = 32; off > 0; off >>= 1) acc += __shfl_down(acc, off);
  if (lane == 0) {
    float dgn = dg[r];
    float z = dgn * (acc + dgn * y[r]) + bptr[0];  // identity (+1) diag term added explicitly
    float t2 = z * z;
    alpha[r] = 1.0f / (1.0f + expf(-t2));
  }
}

// ---------- rank-based exact top-K (ties -> smaller index first, like lax.top_k) ----------
__global__ __launch_bounds__(256) void k_rank(const float* __restrict__ alpha, float* __restrict__ cutv,
                                              float* __restrict__ out_topi, int* __restrict__ sel_cnt) {
  __shared__ unsigned int keys[NN];  // 8 KiB: alpha bits (alpha >= 0.5 > 0 -> bit order == value order)
  int b = blockIdx.x & 7;
  int chunk = blockIdx.x >> 3;
  int t = threadIdx.x;
  if (chunk == 0 && t == 0) sel_cnt[b] = 0;   // replaces the sel_cnt memset dispatch
  const float* ab = alpha + (size_t)b * NN;
  for (int i = t; i < NN; i += 256) keys[i] = __float_as_uint(ab[i]);
  __syncthreads();
  int i = chunk * 256 + t;
  unsigned int ai = keys[i];
  int rank = 0;
  const uint4* k4 = (const uint4*)keys;       // broadcast reads: all lanes same addr, conflict-free
#pragma unroll 4
  for (int j4 = 0; j4 < NN / 4; ++j4) {
    uint4 v = k4[j4];
    int j = j4 * 4;
    rank += (v.x > ai) || (v.x == ai && (j + 0) < i);
    rank += (v.y > ai) || (v.y == ai && (j + 1) < i);
    rank += (v.z > ai) || (v.z == ai && (j + 2) < i);
    rank += (v.w > ai) || (v.w == ai && (j + 3) < i);
  }
  if (rank < KK) out_topi[(size_t)b * KK + rank] = (float)i;
  if (rank == KK - 1) cutv[b] = __uint_as_float(ai);
}

// ---------- cut_alpha + selected-column compaction ----------
__global__ __launch_bounds__(256) void k_selcut(const float* __restrict__ alpha, const float* __restrict__ cutv,
                                                float* __restrict__ cutA, int* __restrict__ selidx,
                                                int* __restrict__ sel_list, int* __restrict__ sel_cnt) {
  int r = blockIdx.x * 256 + threadIdx.x;
  int b = r / NN, n = r % NN;
  float ca = fmaxf(alpha[r] + 1e-7f - cutv[b], 0.0f);
  cutA[r] = ca;
  int s = -1;
  if (ca > 0.f) {
    s = atomicAdd(&sel_cnt[b], 1);
    if (s < SELCAP) sel_list[b * SELCAP + s] = n; else s = -1;
  }
  selidx[r] = s;
}

// ---------- fused: normalized S row -> dense output row + compact Sc row ----------
__global__ __launch_bounds__(256) void k_sbuild(const int2* __restrict__ ell, const int* __restrict__ ell_cnt,
                                                const float* __restrict__ dg, const float* __restrict__ cutA,
                                                const int* __restrict__ selidx, float* __restrict__ inv_eff,
                                                float* __restrict__ Sc, float* __restrict__ outS) {
  __shared__ float row[NN];        // 8 KiB dense S row
  __shared__ float scrow[SELCAP];  // 1 KiB compact row
  __shared__ int   sidx[CAP];
  __shared__ float sterm[CAP];
  __shared__ float wred[4];
  __shared__ float s_inv, s_dv;
  int r = blockIdx.x;  // b*NN + n
  int b = r >> 11;
  int t = threadIdx.x;
  int lane = t & 63, wv = t >> 6;
#pragma unroll
  for (int j = 0; j < NN / 256; ++j) row[t + j * 256] = 0.f;
  if (t < SELCAP) scrow[t] = 0.f;
  int cnt = ell_cnt[r];
  size_t base = (size_t)r * CAP;
  float dgn = dg[r];
  const float* dgb = dg + (size_t)b * NN;
  const float* cab = cutA + (size_t)b * NN;
  const int* sib = selidx + (size_t)b * NN;
  float part = 0.f;
  for (int j = t; j < cnt; j += 256) {
    int2 e = ell[base + j];
    float term = dgn * __int_as_float(e.y) * dgb[e.x] * cab[e.x];
    sidx[j] = e.x; sterm[j] = term;
    part += term;
  }
#pragma unroll
  for (int off = 32; off > 0; off >>= 1) part += __shfl_down(part, off);
  if (lane == 0) wred[wv] = part;
  __syncthreads();
  if (t == 0) {
    float diag = dgn * dgn * cutA[r];                 // "+I" diag of A_hat, col n
    float rho = wred[0] + wred[1] + wred[2] + wred[3] + diag;  // L1 row sum (all >= 0)
    float inv = (cnt > 0) ? (1.0f / fmaxf(rho, 1e-12f)) : 0.f;  // mask (adj rowsum>0 <=> cnt>0) * normalize
    s_inv = inv; s_dv = diag * inv;
    inv_eff[r] = inv;
  }
  __syncthreads();
  float inv = s_inv;
  for (int j = t; j < cnt; j += 256) {               // distinct m per j -> no conflicts
    float v = sterm[j] * inv;
    row[sidx[j]] = v;
    int si = sib[sidx[j]];
    if (si >= 0) scrow[si] = v;
  }
  __syncthreads();
  if (t == 0) {                                       // diag after barrier: safe vs self-loop overlap
    int n = r & (NN - 1);
    row[n] += s_dv;
    int si = sib[n];
    if (si >= 0) scrow[si] += s_dv;
  }
  __syncthreads();
  float4* dst = (float4*)(outS + (size_t)r * NN);
  const float4* src = (const float4*)row;
#pragma unroll
  for (int j = 0; j < NN / 4 / 256; ++j) dst[t + j * 256] = src[t + j * 256];
  if (t < SELCAP) Sc[(size_t)r * SELCAP + t] = scrow[t];
}

// ---------- M[n, :] = sum_k adj[n,k] * Sc[k, :]  (dense-compact; batch pinned to XCD) ----------
__global__ __launch_bounds__(256) void k_M(const int2* __restrict__ ell, const int* __restrict__ ell_cnt,
                                           const float* __restrict__ Sc, float* __restrict__ Mmat) {
  int b = blockIdx.x & 7;           // batch -> XCD: Sc[b] (2 MB) stays L2-resident
  int n = blockIdx.x >> 3;
  int r = b * NN + n;
  int t = threadIdx.x;
  __shared__ int srk[CAP];
  __shared__ float sav[CAP];
  int cnt = ell_cnt[r];
  size_t base = (size_t)r * CAP;
  for (int e = t; e < cnt; e += 256) {
    int2 p = ell[base + e];
    srk[e] = b * NN + p.x;
    sav[e] = __int_as_float(p.y);
  }
  __syncthreads();
  float a0 = 0.f, a1 = 0.f, a2 = 0.f, a3 = 0.f;     // 4-way MLP on the Sc gathers
  int e = 0;
  for (; e + 4 <= cnt; e += 4) {
    a0 += sav[e + 0] * Sc[(size_t)srk[e + 0] * SELCAP + t];
    a1 += sav[e + 1] * Sc[(size_t)srk[e + 1] * SELCAP + t];
    a2 += sav[e + 2] * Sc[(size_t)srk[e + 2] * SELCAP + t];
    a3 += sav[e + 3] * Sc[(size_t)srk[e + 3] * SELCAP + t];
  }
  for (; e < cnt; ++e) a0 += sav[e] * Sc[(size_t)srk[e] * SELCAP + t];
  Mmat[(size_t)r * SELCAP + t] = (a0 + a1) + (a2 + a3);
}

// ---------- full-grid epilogue: every row of xc and coarse written (no memset needed) ----------
__global__ __launch_bounds__(256) void k_epi2(const float* __restrict__ x, const int2* __restrict__ ell,
                                              const int* __restrict__ ell_cnt, const float* __restrict__ dg,
                                              const float* __restrict__ cutA, const float* __restrict__ inv_eff,
                                              const int* __restrict__ selidx, const int* __restrict__ sel_list,
                                              const int* __restrict__ sel_cnt, const float* __restrict__ Mmat,
                                              float* __restrict__ xc, float* __restrict__ coarse) {
  int b = blockIdx.x & 7;           // batch -> XCD: x[b], Mmat[b] (2 MB each) stay L2-resident
  int m = blockIdx.x >> 3;
  int rm = b * NN + m;
  int t = threadIdx.x;
  __shared__ float row[NN];         // 8 KiB coarse row
  __shared__ int cn[CAP + 1];
  __shared__ float cw[CAP + 1];
  bool sel = selidx[rm] >= 0;       // block-uniform
  if (!sel) {                       // ~90% of rows: stream zeros, no LDS at all
    float4 z = make_float4(0.f, 0.f, 0.f, 0.f);
    if (t < FD / 4) ((float4*)(xc + (size_t)rm * FD))[t] = z;
    float4* dco = (float4*)(coarse + (size_t)rm * NN);
    dco[t] = z;
    dco[t + 256] = z;
    return;
  }
  int nsel = sel_cnt[b]; if (nsel > SELCAP) nsel = SELCAP;
  int cnt = ell_cnt[rm];
#pragma unroll
  for (int j = 0; j < NN / 256; ++j) row[t + j * 256] = 0.f;
  {
    float dgm = dg[rm], cam = cutA[rm];
    // column m of S == row m of adj (exact symmetry) plus the diagonal (+1) entry
    for (int j = t; j <= cnt; j += 256) {
      if (j < cnt) {
        int2 e = ell[(size_t)rm * CAP + j];
        cn[j] = b * NN + e.x;
        cw[j] = __int_as_float(e.y) * dg[b * NN + e.x] * dgm * cam * inv_eff[b * NN + e.x];
      } else {
        cn[j] = rm;
        cw[j] = dgm * dgm * cam * inv_eff[rm];
      }
    }
  }
  __syncthreads();
  float axc = 0.f, aco = 0.f;
  for (int e = 0; e <= cnt; ++e) {
    float w = cw[e];
    if (w == 0.f) continue;
    size_t rn = (size_t)cn[e];
    axc += w * x[rn * FD + t];
    aco += w * Mmat[rn * SELCAP + t];
  }
  if (t < nsel) row[sel_list[b * SELCAP + t]] = floorf(aco * 10000.0f) / 10000.0f;
  xc[(size_t)rm * FD + t] = axc;
  __syncthreads();
  float4* dst = (float4*)(coarse + (size_t)rm * NN);
  const float4* src = (const float4*)row;
#pragma unroll
  for (int j = 0; j < NN / 4 / 256; ++j) dst[t + j * 256] = src[t + j * 256];
}

extern "C" void kernel_launch(void* const* d_in, const int* in_sizes, int n_in,
                              void* d_out, int out_size, void* d_ws, size_t ws_size,
                              hipStream_t stream) {
  (void)in_sizes; (void)n_in; (void)ws_size; (void)out_size;
  const float* x = (const float*)d_in[0];
  const float* adj = (const float*)d_in[1];
  const float* W = (const float*)d_in[2];
  const float* bptr = (const float*)d_in[3];

  float* out = (float*)d_out;
  const size_t XC_SZ = (size_t)BB * NN * FD;   // 4,194,304
  const size_t CO_SZ = (size_t)BB * NN * NN;   // 33,554,432
  const size_t S_SZ  = (size_t)BB * NN * NN;   // 33,554,432
  float* out_xc = out;
  float* out_co = out + XC_SZ;
  float* out_S  = out + XC_SZ + CO_SZ;
  float* out_ti = out + XC_SZ + CO_SZ + S_SZ;  // topi as float (written fully by k_rank)

  char* w = (char*)d_ws;
  int2*  ell     = (int2*)w;  w += (size_t)BB * NN * CAP * 8;
  float* Sc      = (float*)w; w += (size_t)BB * NN * SELCAP * 4;
  float* Mmat    = (float*)w; w += (size_t)BB * NN * SELCAP * 4;
  int*   ell_cnt = (int*)w;   w += (size_t)BB * NN * 4;
  float* dg      = (float*)w; w += (size_t)BB * NN * 4;
  float* yv      = (float*)w; w += (size_t)BB * NN * 4;
  float* alpha   = (float*)w; w += (size_t)BB * NN * 4;
  float* cutA    = (float*)w; w += (size_t)BB * NN * 4;
  float* inv_eff = (float*)w; w += (size_t)BB * NN * 4;
  int*   selidx  = (int*)w;   w += (size_t)BB * NN * 4;
  float* cutv    = (float*)w; w += (size_t)BB * 4;
  int*   sel_cnt = (int*)w;   w += (size_t)BB * 4;
  int*   sel_list= (int*)w;   w += (size_t)BB * SELCAP * 4;

  // every output byte written by kernels: xc+coarse by k_epi2, S by k_sbuild, topi by k_rank
  k_spy<<<BB * NN, 256, 0, stream>>>(adj, x, W, ell, ell_cnt, dg, yv);
  k_alpha<<<BB * NN / 4, 256, 0, stream>>>(ell, ell_cnt, dg, yv, bptr, alpha);
  k_rank<<<BB * 8, 256, 0, stream>>>(alpha, cutv, out_ti, sel_cnt);
  k_selcut<<<BB * NN / 256, 256, 0, stream>>>(alpha, cutv, cutA, selidx, sel_list, sel_cnt);
  k_sbuild<<<BB * NN, 256, 0, stream>>>(ell, ell_cnt, dg, cutA, selidx, inv_eff, Sc, out_S);
  k_M<<<BB * NN, 256, 0, stream>>>(ell, ell_cnt, Sc, Mmat);
  k_epi2<<<BB * NN, 256, 0, stream>>>(x, ell, ell_cnt, dg, cutA, inv_eff,
                                      selidx, sel_list, sel_cnt, Mmat, out_xc, out_co);
}

// Round 10
// 512.382 us; speedup vs baseline: 1.1190x; 1.0500x over previous
//
#include <hip/hip_runtime.h>
#include <cstdint>
#include <cstddef>

#define BB 8
#define NN 2048
#define FD 256
#define KK 205      // int(2048*0.1)+1
#define CAP 96      // max nnz per adj row (mean ~41, P(>96) ~ 1e-15)
#define SELCAP 256  // max selected columns (nsel ~205; clamped if ever exceeded)

typedef float f4 __attribute__((ext_vector_type(4)));  // native vec4: valid for nontemporal builtins

// Packed ELL entry: x = column index, y = __float_as_int(value)

// ---------- fused: ELL sparsify of adj (ballot compaction) + row sum + dg + y = x.W ----------
__global__ __launch_bounds__(256) void k_spy(const float* __restrict__ adj, const float* __restrict__ x,
                                             const float* __restrict__ W, int2* __restrict__ ell,
                                             int* __restrict__ ell_cnt, float* __restrict__ dg,
                                             float* __restrict__ y) {
  int r = blockIdx.x;  // b*NN + n
  const f4* arow4 = (const f4*)(adj + (size_t)r * NN);
  int t = threadIdx.x;
  int lane = t & 63, wv = t >> 6;
  __shared__ int counter;
  __shared__ float wsum[4], wy[4];
  if (t == 0) counter = 0;
  __syncthreads();
  size_t base = (size_t)r * CAP;
  unsigned long long lmask = (1ull << lane) - 1;   // lane<=63 -> no UB
  float ls = 0.f;
#pragma unroll
  for (int j = 0; j < 2; ++j) {
    int i4 = t + j * 256;
    f4 v = __builtin_nontemporal_load(&arow4[i4]);  // read-once stream: don't pollute L2
    int m0 = i4 * 4;
#pragma unroll
    for (int c = 0; c < 4; ++c) {
      float val = v[c];
      unsigned long long mk = __ballot(val != 0.f);
      if (mk) {
        int wbase = 0;
        if (lane == 0) wbase = atomicAdd(&counter, (int)__popcll(mk));
        wbase = __shfl(wbase, 0);                  // one atomic per wave per component
        if (val != 0.f) {
          int p = wbase + (int)__popcll(mk & lmask);
          if (p < CAP) ell[base + p] = make_int2(m0 + c, __float_as_int(val));
        }
      }
      ls += val;                                   // val==0 adds nothing
    }
  }
#pragma unroll
  for (int off = 32; off > 0; off >>= 1) ls += __shfl_down(ls, off);
  if (lane == 0) wsum[wv] = ls;
  float xv = x[(size_t)r * FD + t] * W[t];
#pragma unroll
  for (int off = 32; off > 0; off >>= 1) xv += __shfl_down(xv, off);
  if (lane == 0) wy[wv] = xv;
  __syncthreads();
  if (t == 0) {
    int tot = counter; if (tot > CAP) tot = CAP;
    ell_cnt[r] = tot;
    float rs = wsum[0] + wsum[1] + wsum[2] + wsum[3];
    dg[r] = 1.0f / sqrtf(1.0f + rs);  // A_hat row sum = 1 + adj row sum >= 1 (clip is a no-op)
    y[r] = wy[0] + wy[1] + wy[2] + wy[3];
  }
}

// ---------- alpha[b,n] = sigmoid((dg[n]*(sum_m A_hat[n,m]*dg[m]*y[m]) + b)^2) ----------
__global__ __launch_bounds__(256) void k_alpha(const int2* __restrict__ ell, const int* __restrict__ ell_cnt,
                                               const float* __restrict__ dg, const float* __restrict__ y,
                                               const float* __restrict__ bptr, float* __restrict__ alpha) {
  int lane = threadIdx.x & 63, wv = threadIdx.x >> 6;
  int r = blockIdx.x * 4 + wv;
  int b = r / NN;
  int cnt = ell_cnt[r];
  size_t base = (size_t)r * CAP;
  const float* dgb = dg + (size_t)b * NN;
  const float* yb = y + (size_t)b * NN;
  float acc = 0.f;
  for (int j = lane; j < cnt; j += 64) {
    int2 e = ell[base + j];
    acc += __int_as_float(e.y) * dgb[e.x] * yb[e.x];
  }
#pragma unroll
  for (int off = 32; off > 0; off >>= 1) acc += __shfl_down(acc, off);
  if (lane == 0) {
    float dgn = dg[r];
    float z = dgn * (acc + dgn * y[r]) + bptr[0];  // identity (+1) diag term added explicitly
    float t2 = z * z;
    alpha[r] = 1.0f / (1.0f + expf(-t2));
  }
}

// ---------- rank-based exact top-K (ties -> smaller index first, like lax.top_k) ----------
__global__ __launch_bounds__(256) void k_rank(const float* __restrict__ alpha, float* __restrict__ cutv,
                                              float* __restrict__ out_topi, int* __restrict__ sel_cnt) {
  __shared__ unsigned int keys[NN];  // 8 KiB: alpha bits (alpha >= 0.5 > 0 -> bit order == value order)
  int b = blockIdx.x & 7;
  int chunk = blockIdx.x >> 3;
  int t = threadIdx.x;
  if (chunk == 0 && t == 0) sel_cnt[b] = 0;   // replaces the sel_cnt memset dispatch
  const float* ab = alpha + (size_t)b * NN;
  for (int i = t; i < NN; i += 256) keys[i] = __float_as_uint(ab[i]);
  __syncthreads();
  int i = chunk * 256 + t;
  unsigned int ai = keys[i];
  int rank = 0;
  const uint4* k4 = (const uint4*)keys;       // broadcast reads: all lanes same addr, conflict-free
#pragma unroll 4
  for (int j4 = 0; j4 < NN / 4; ++j4) {
    uint4 v = k4[j4];
    int j = j4 * 4;
    rank += (v.x > ai) || (v.x == ai && (j + 0) < i);
    rank += (v.y > ai) || (v.y == ai && (j + 1) < i);
    rank += (v.z > ai) || (v.z == ai && (j + 2) < i);
    rank += (v.w > ai) || (v.w == ai && (j + 3) < i);
  }
  if (rank < KK) out_topi[(size_t)b * KK + rank] = (float)i;
  if (rank == KK - 1) cutv[b] = __uint_as_float(ai);
}

// ---------- cut_alpha + selected-column compaction ----------
__global__ __launch_bounds__(256) void k_selcut(const float* __restrict__ alpha, const float* __restrict__ cutv,
                                                float* __restrict__ cutA, int* __restrict__ selidx,
                                                int* __restrict__ sel_list, int* __restrict__ sel_cnt) {
  int r = blockIdx.x * 256 + threadIdx.x;
  int b = r / NN, n = r % NN;
  float ca = fmaxf(alpha[r] + 1e-7f - cutv[b], 0.0f);
  cutA[r] = ca;
  int s = -1;
  if (ca > 0.f) {
    s = atomicAdd(&sel_cnt[b], 1);
    if (s < SELCAP) sel_list[b * SELCAP + s] = n; else s = -1;
  }
  selidx[r] = s;
}

// ---------- fused: normalized S row -> dense output row (nt) + compact Sc row (cached) ----------
__global__ __launch_bounds__(256) void k_sbuild(const int2* __restrict__ ell, const int* __restrict__ ell_cnt,
                                                const float* __restrict__ dg, const float* __restrict__ cutA,
                                                const int* __restrict__ selidx, float* __restrict__ inv_eff,
                                                float* __restrict__ Sc, float* __restrict__ outS) {
  __shared__ float row[NN];        // 8 KiB dense S row
  __shared__ float scrow[SELCAP];  // 1 KiB compact row
  __shared__ int   sidx[CAP];
  __shared__ float sterm[CAP];
  __shared__ float wred[4];
  __shared__ float s_inv, s_dv;
  int r = blockIdx.x;  // b*NN + n
  int b = r >> 11;
  int t = threadIdx.x;
  int lane = t & 63, wv = t >> 6;
#pragma unroll
  for (int j = 0; j < NN / 256; ++j) row[t + j * 256] = 0.f;
  if (t < SELCAP) scrow[t] = 0.f;
  int cnt = ell_cnt[r];
  size_t base = (size_t)r * CAP;
  float dgn = dg[r];
  const float* dgb = dg + (size_t)b * NN;
  const float* cab = cutA + (size_t)b * NN;
  const int* sib = selidx + (size_t)b * NN;
  float part = 0.f;
  for (int j = t; j < cnt; j += 256) {
    int2 e = ell[base + j];
    float term = dgn * __int_as_float(e.y) * dgb[e.x] * cab[e.x];
    sidx[j] = e.x; sterm[j] = term;
    part += term;
  }
#pragma unroll
  for (int off = 32; off > 0; off >>= 1) part += __shfl_down(part, off);
  if (lane == 0) wred[wv] = part;
  __syncthreads();
  if (t == 0) {
    float diag = dgn * dgn * cutA[r];                 // "+I" diag of A_hat, col n
    float rho = wred[0] + wred[1] + wred[2] + wred[3] + diag;  // L1 row sum (all >= 0)
    float inv = (cnt > 0) ? (1.0f / fmaxf(rho, 1e-12f)) : 0.f;  // mask (adj rowsum>0 <=> cnt>0) * normalize
    s_inv = inv; s_dv = diag * inv;
    inv_eff[r] = inv;
  }
  __syncthreads();
  float inv = s_inv;
  for (int j = t; j < cnt; j += 256) {               // distinct m per j -> no conflicts
    float v = sterm[j] * inv;
    row[sidx[j]] = v;
    int si = sib[sidx[j]];
    if (si >= 0) scrow[si] = v;
  }
  __syncthreads();
  if (t == 0) {                                       // diag after barrier: safe vs self-loop overlap
    int n = r & (NN - 1);
    row[n] += s_dv;
    int si = sib[n];
    if (si >= 0) scrow[si] += s_dv;
  }
  __syncthreads();
  f4* dst = (f4*)(outS + (size_t)r * NN);
  const f4* src = (const f4*)row;
#pragma unroll
  for (int j = 0; j < NN / 4 / 256; ++j)
    __builtin_nontemporal_store(src[t + j * 256], &dst[t + j * 256]);  // stream S out, keep Sc in L2
  if (t < SELCAP) Sc[(size_t)r * SELCAP + t] = scrow[t];
}

// ---------- M[n, :] = sum_k adj[n,k] * Sc[k, :]  (dense-compact; batch pinned to XCD) ----------
__global__ __launch_bounds__(256) void k_M(const int2* __restrict__ ell, const int* __restrict__ ell_cnt,
                                           const float* __restrict__ Sc, float* __restrict__ Mmat) {
  int b = blockIdx.x & 7;           // batch -> XCD: Sc[b] (2 MB) stays L2-resident
  int n = blockIdx.x >> 3;
  int r = b * NN + n;
  int t = threadIdx.x;
  __shared__ int srk[CAP];
  __shared__ float sav[CAP];
  int cnt = ell_cnt[r];
  size_t base = (size_t)r * CAP;
  for (int e = t; e < cnt; e += 256) {
    int2 p = ell[base + e];
    srk[e] = b * NN + p.x;
    sav[e] = __int_as_float(p.y);
  }
  __syncthreads();
  float a0 = 0.f, a1 = 0.f, a2 = 0.f, a3 = 0.f;     // 4-way MLP on the Sc gathers
  int e = 0;
  for (; e + 4 <= cnt; e += 4) {
    a0 += sav[e + 0] * Sc[(size_t)srk[e + 0] * SELCAP + t];
    a1 += sav[e + 1] * Sc[(size_t)srk[e + 1] * SELCAP + t];
    a2 += sav[e + 2] * Sc[(size_t)srk[e + 2] * SELCAP + t];
    a3 += sav[e + 3] * Sc[(size_t)srk[e + 3] * SELCAP + t];
  }
  for (; e < cnt; ++e) a0 += sav[e] * Sc[(size_t)srk[e] * SELCAP + t];
  Mmat[(size_t)r * SELCAP + t] = (a0 + a1) + (a2 + a3);
}

// ---------- full-grid epilogue: every row of xc and coarse written (no memset needed) ----------
__global__ __launch_bounds__(256) void k_epi2(const float* __restrict__ x, const int2* __restrict__ ell,
                                              const int* __restrict__ ell_cnt, const float* __restrict__ dg,
                                              const float* __restrict__ cutA, const float* __restrict__ inv_eff,
                                              const int* __restrict__ selidx, const int* __restrict__ sel_list,
                                              const int* __restrict__ sel_cnt, const float* __restrict__ Mmat,
                                              float* __restrict__ xc, float* __restrict__ coarse) {
  int b = blockIdx.x & 7;           // batch -> XCD: x[b], Mmat[b] (2 MB each) stay L2-resident
  int m = blockIdx.x >> 3;
  int rm = b * NN + m;
  int t = threadIdx.x;
  __shared__ float row[NN];         // 8 KiB coarse row
  __shared__ int cn[CAP + 1];
  __shared__ float cw[CAP + 1];
  bool sel = selidx[rm] >= 0;       // block-uniform
  if (!sel) {                       // ~90% of rows: stream zeros, no LDS at all
    f4 z = (f4)(0.f);
    if (t < FD / 4) __builtin_nontemporal_store(z, &((f4*)(xc + (size_t)rm * FD))[t]);
    f4* dco = (f4*)(coarse + (size_t)rm * NN);
    __builtin_nontemporal_store(z, &dco[t]);
    __builtin_nontemporal_store(z, &dco[t + 256]);
    return;
  }
  int nsel = sel_cnt[b]; if (nsel > SELCAP) nsel = SELCAP;
  int cnt = ell_cnt[rm];
#pragma unroll
  for (int j = 0; j < NN / 256; ++j) row[t + j * 256] = 0.f;
  {
    float dgm = dg[rm], cam = cutA[rm];
    // column m of S == row m of adj (exact symmetry) plus the diagonal (+1) entry
    for (int j = t; j <= cnt; j += 256) {
      if (j < cnt) {
        int2 e = ell[(size_t)rm * CAP + j];
        cn[j] = b * NN + e.x;
        cw[j] = __int_as_float(e.y) * dg[b * NN + e.x] * dgm * cam * inv_eff[b * NN + e.x];
      } else {
        cn[j] = rm;
        cw[j] = dgm * dgm * cam * inv_eff[rm];
      }
    }
  }
  __syncthreads();
  float axc = 0.f, aco = 0.f;
  for (int e = 0; e <= cnt; ++e) {
    float w = cw[e];
    if (w == 0.f) continue;
    size_t rn = (size_t)cn[e];
    axc += w * x[rn * FD + t];
    aco += w * Mmat[rn * SELCAP + t];
  }
  if (t < nsel) row[sel_list[b * SELCAP + t]] = floorf(aco * 10000.0f) / 10000.0f;
  __builtin_nontemporal_store(axc, &xc[(size_t)rm * FD + t]);
  __syncthreads();
  f4* dst = (f4*)(coarse + (size_t)rm * NN);
  const f4* src = (const f4*)row;
#pragma unroll
  for (int j = 0; j < NN / 4 / 256; ++j)
    __builtin_nontemporal_store(src[t + j * 256], &dst[t + j * 256]);  // stream coarse out
}

extern "C" void kernel_launch(void* const* d_in, const int* in_sizes, int n_in,
                              void* d_out, int out_size, void* d_ws, size_t ws_size,
                              hipStream_t stream) {
  (void)in_sizes; (void)n_in; (void)ws_size; (void)out_size;
  const float* x = (const float*)d_in[0];
  const float* adj = (const float*)d_in[1];
  const float* W = (const float*)d_in[2];
  const float* bptr = (const float*)d_in[3];

  float* out = (float*)d_out;
  const size_t XC_SZ = (size_t)BB * NN * FD;   // 4,194,304
  const size_t CO_SZ = (size_t)BB * NN * NN;   // 33,554,432
  const size_t S_SZ  = (size_t)BB * NN * NN;   // 33,554,432
  float* out_xc = out;
  float* out_co = out + XC_SZ;
  float* out_S  = out + XC_SZ + CO_SZ;
  float* out_ti = out + XC_SZ + CO_SZ + S_SZ;  // topi as float (written fully by k_rank)

  char* w = (char*)d_ws;
  int2*  ell     = (int2*)w;  w += (size_t)BB * NN * CAP * 8;
  float* Sc      = (float*)w; w += (size_t)BB * NN * SELCAP * 4;
  float* Mmat    = (float*)w; w += (size_t)BB * NN * SELCAP * 4;
  int*   ell_cnt = (int*)w;   w += (size_t)BB * NN * 4;
  float* dg      = (float*)w; w += (size_t)BB * NN * 4;
  float* yv      = (float*)w; w += (size_t)BB * NN * 4;
  float* alpha   = (float*)w; w += (size_t)BB * NN * 4;
  float* cutA    = (float*)w; w += (size_t)BB * NN * 4;
  float* inv_eff = (float*)w; w += (size_t)BB * NN * 4;
  int*   selidx  = (int*)w;   w += (size_t)BB * NN * 4;
  float* cutv    = (float*)w; w += (size_t)BB * 4;
  int*   sel_cnt = (int*)w;   w += (size_t)BB * 4;
  int*   sel_list= (int*)w;   w += (size_t)BB * SELCAP * 4;

  // every output byte written by kernels: xc+coarse by k_epi2, S by k_sbuild, topi by k_rank
  k_spy<<<BB * NN, 256, 0, stream>>>(adj, x, W, ell, ell_cnt, dg, yv);
  k_alpha<<<BB * NN / 4, 256, 0, stream>>>(ell, ell_cnt, dg, yv, bptr, alpha);
  k_rank<<<BB * 8, 256, 0, stream>>>(alpha, cutv, out_ti, sel_cnt);
  k_selcut<<<BB * NN / 256, 256, 0, stream>>>(alpha, cutv, cutA, selidx, sel_list, sel_cnt);
  k_sbuild<<<BB * NN, 256, 0, stream>>>(ell, ell_cnt, dg, cutA, selidx, inv_eff, Sc, out_S);
  k_M<<<BB * NN, 256, 0, stream>>>(ell, ell_cnt, Sc, Mmat);
  k_epi2<<<BB * NN, 256, 0, stream>>>(x, ell, ell_cnt, dg, cutA, inv_eff,
                                      selidx, sel_list, sel_cnt, Mmat, out_xc, out_co);
}

// Round 11
// 511.176 us; speedup vs baseline: 1.1217x; 1.0024x over previous
//
#include <hip/hip_runtime.h>
#include <cstdint>
#include <cstddef>

#define BB 8
#define NN 2048
#define FD 256
#define KK 205      // int(2048*0.1)+1
#define CAP 96      // max nnz per adj row (mean ~41, P(>96) ~ 1e-15)
#define SELCAP 256  // max selected columns (nsel ~205; clamped if ever exceeded)

typedef float f4 __attribute__((ext_vector_type(4)));  // native vec4: valid for nontemporal builtins

// Packed ELL entry: x = column index, y = __float_as_int(value)
// Packed sel entry: x = __float_as_int(dg*cutA), y = selidx

// ---------- fused: ELL sparsify of adj (ballot compaction) + row sum + dg + y = x.W + dgy ----------
__global__ __launch_bounds__(256) void k_spy(const float* __restrict__ adj, const float* __restrict__ x,
                                             const float* __restrict__ W, int2* __restrict__ ell,
                                             int* __restrict__ ell_cnt, float* __restrict__ dg,
                                             float* __restrict__ dgy) {
  int r = blockIdx.x;  // b*NN + n
  const f4* arow4 = (const f4*)(adj + (size_t)r * NN);
  int t = threadIdx.x;
  int lane = t & 63, wv = t >> 6;
  __shared__ int counter;
  __shared__ float wsum[4], wy[4];
  if (t == 0) counter = 0;
  __syncthreads();
  size_t base = (size_t)r * CAP;
  unsigned long long lmask = (1ull << lane) - 1;   // lane<=63 -> no UB
  float ls = 0.f;
#pragma unroll
  for (int j = 0; j < 2; ++j) {
    int i4 = t + j * 256;
    f4 v = __builtin_nontemporal_load(&arow4[i4]);  // read-once stream: don't pollute L2
    int m0 = i4 * 4;
#pragma unroll
    for (int c = 0; c < 4; ++c) {
      float val = v[c];
      unsigned long long mk = __ballot(val != 0.f);
      if (mk) {
        int wbase = 0;
        if (lane == 0) wbase = atomicAdd(&counter, (int)__popcll(mk));
        wbase = __shfl(wbase, 0);                  // one atomic per wave per component
        if (val != 0.f) {
          int p = wbase + (int)__popcll(mk & lmask);
          if (p < CAP) ell[base + p] = make_int2(m0 + c, __float_as_int(val));
        }
      }
      ls += val;                                   // val==0 adds nothing
    }
  }
#pragma unroll
  for (int off = 32; off > 0; off >>= 1) ls += __shfl_down(ls, off);
  if (lane == 0) wsum[wv] = ls;
  float xv = x[(size_t)r * FD + t] * W[t];
#pragma unroll
  for (int off = 32; off > 0; off >>= 1) xv += __shfl_down(xv, off);
  if (lane == 0) wy[wv] = xv;
  __syncthreads();
  if (t == 0) {
    int tot = counter; if (tot > CAP) tot = CAP;
    ell_cnt[r] = tot;
    float rs = wsum[0] + wsum[1] + wsum[2] + wsum[3];
    float d = 1.0f / sqrtf(1.0f + rs);  // A_hat row sum = 1 + adj row sum >= 1 (clip is a no-op)
    dg[r] = d;
    dgy[r] = d * (wy[0] + wy[1] + wy[2] + wy[3]);  // fused product: one gather in k_alpha
  }
}

// ---------- alpha[b,n] = sigmoid((dg[n]*(sum_m A_hat[n,m]*dg[m]*y[m]) + b)^2) ----------
__global__ __launch_bounds__(256) void k_alpha(const int2* __restrict__ ell, const int* __restrict__ ell_cnt,
                                               const float* __restrict__ dg, const float* __restrict__ dgy,
                                               const float* __restrict__ bptr, float* __restrict__ alpha) {
  int lane = threadIdx.x & 63, wv = threadIdx.x >> 6;
  int r = blockIdx.x * 4 + wv;
  int b = r / NN;
  int cnt = ell_cnt[r];
  size_t base = (size_t)r * CAP;
  const float* gyb = dgy + (size_t)b * NN;
  float acc = 0.f;
  for (int j = lane; j < cnt; j += 64) {
    int2 e = ell[base + j];
    acc += __int_as_float(e.y) * gyb[e.x];        // single gather per entry
  }
#pragma unroll
  for (int off = 32; off > 0; off >>= 1) acc += __shfl_down(acc, off);
  if (lane == 0) {
    float dgn = dg[r];
    float z = dgn * (acc + dgy[r]) + bptr[0];     // diag: dgn * (dgn*y[r]) = dgn * dgy[r]
    float t2 = z * z;
    alpha[r] = 1.0f / (1.0f + expf(-t2));
  }
}

// ---------- rank-based exact top-K (ties -> smaller index first, like lax.top_k) ----------
__global__ __launch_bounds__(256) void k_rank(const float* __restrict__ alpha, float* __restrict__ cutv,
                                              float* __restrict__ out_topi, int* __restrict__ sel_cnt) {
  __shared__ unsigned int keys[NN];  // 8 KiB: alpha bits (alpha >= 0.5 > 0 -> bit order == value order)
  int b = blockIdx.x & 7;
  int chunk = blockIdx.x >> 3;
  int t = threadIdx.x;
  if (chunk == 0 && t == 0) sel_cnt[b] = 0;   // replaces the sel_cnt memset dispatch
  const float* ab = alpha + (size_t)b * NN;
  for (int i = t; i < NN; i += 256) keys[i] = __float_as_uint(ab[i]);
  __syncthreads();
  int i = chunk * 256 + t;
  unsigned int ai = keys[i];
  int rank = 0;
  const uint4* k4 = (const uint4*)keys;       // broadcast reads: all lanes same addr, conflict-free
#pragma unroll 4
  for (int j4 = 0; j4 < NN / 4; ++j4) {
    uint4 v = k4[j4];
    int j = j4 * 4;
    rank += (v.x > ai) || (v.x == ai && (j + 0) < i);
    rank += (v.y > ai) || (v.y == ai && (j + 1) < i);
    rank += (v.z > ai) || (v.z == ai && (j + 2) < i);
    rank += (v.w > ai) || (v.w == ai && (j + 3) < i);
  }
  if (rank < KK) out_topi[(size_t)b * KK + rank] = (float)i;
  if (rank == KK - 1) cutv[b] = __uint_as_float(ai);
}

// ---------- cut_alpha + selected compaction + packed {dgca, selidx} ----------
__global__ __launch_bounds__(256) void k_selcut(const float* __restrict__ alpha, const float* __restrict__ cutv,
                                                const float* __restrict__ dg, int2* __restrict__ seldg,
                                                int* __restrict__ sel_list, int* __restrict__ sel_cnt) {
  int r = blockIdx.x * 256 + threadIdx.x;
  int b = r / NN, n = r % NN;
  float ca = fmaxf(alpha[r] + 1e-7f - cutv[b], 0.0f);
  int s = -1;
  if (ca > 0.f) {
    s = atomicAdd(&sel_cnt[b], 1);
    if (s < SELCAP) sel_list[b * SELCAP + s] = n; else s = -1;
  }
  seldg[r] = make_int2(__float_as_int(dg[r] * ca), s);  // one 8B gather serves k_sbuild
}

// ---------- fused: normalized S row -> dense output row (nt) + compact Sc row + dginv ----------
__global__ __launch_bounds__(256) void k_sbuild(const int2* __restrict__ ell, const int* __restrict__ ell_cnt,
                                                const float* __restrict__ dg, const int2* __restrict__ seldg,
                                                float* __restrict__ dginv,
                                                float* __restrict__ Sc, float* __restrict__ outS) {
  __shared__ float row[NN];        // 8 KiB dense S row
  __shared__ float scrow[SELCAP];  // 1 KiB compact row
  __shared__ int   sidx[CAP];      // column m
  __shared__ int   ssel[CAP];      // selidx of m
  __shared__ float sterm[CAP];
  __shared__ float wred[4];
  __shared__ float s_inv, s_dv;
  int r = blockIdx.x;  // b*NN + n
  int b = r >> 11;
  int t = threadIdx.x;
  int lane = t & 63, wv = t >> 6;
#pragma unroll
  for (int j = 0; j < NN / 256; ++j) row[t + j * 256] = 0.f;
  if (t < SELCAP) scrow[t] = 0.f;
  int cnt = ell_cnt[r];
  size_t base = (size_t)r * CAP;
  float dgn = dg[r];
  const int2* sdb = seldg + (size_t)b * NN;
  float part = 0.f;
  for (int j = t; j < cnt; j += 256) {
    int2 e = ell[base + j];
    int2 sd = sdb[e.x];                               // single 8B gather: {dg*cutA, selidx}
    float term = dgn * __int_as_float(e.y) * __int_as_float(sd.x);
    sidx[j] = e.x; ssel[j] = sd.y; sterm[j] = term;
    part += term;
  }
#pragma unroll
  for (int off = 32; off > 0; off >>= 1) part += __shfl_down(part, off);
  if (lane == 0) wred[wv] = part;
  __syncthreads();
  if (t == 0) {
    float diag = dgn * __int_as_float(sdb[r & (NN - 1)].x);  // dgn * dg[n]*cutA[n]
    float rho = wred[0] + wred[1] + wred[2] + wred[3] + diag;  // L1 row sum (all >= 0)
    float inv = (cnt > 0) ? (1.0f / fmaxf(rho, 1e-12f)) : 0.f;  // mask (adj rowsum>0 <=> cnt>0) * normalize
    s_inv = inv; s_dv = diag * inv;
    dginv[r] = dgn * inv;                             // fused product: one gather in k_epi2
  }
  __syncthreads();
  float inv = s_inv;
  for (int j = t; j < cnt; j += 256) {               // distinct m per j -> no conflicts
    float v = sterm[j] * inv;
    row[sidx[j]] = v;
    int si = ssel[j];
    if (si >= 0) scrow[si] = v;
  }
  __syncthreads();
  if (t == 0) {                                       // diag after barrier: safe vs self-loop overlap
    int n = r & (NN - 1);
    row[n] += s_dv;
    int si = sdb[n].y;
    if (si >= 0) scrow[si] += s_dv;
  }
  __syncthreads();
  f4* dst = (f4*)(outS + (size_t)r * NN);
  const f4* src = (const f4*)row;
#pragma unroll
  for (int j = 0; j < NN / 4 / 256; ++j)
    __builtin_nontemporal_store(src[t + j * 256], &dst[t + j * 256]);  // stream S out, keep Sc in L2
  if (t < SELCAP) Sc[(size_t)r * SELCAP + t] = scrow[t];
}

// ---------- M[n, :] = sum_k adj[n,k] * Sc[k, :]  (dense-compact; batch pinned to XCD) ----------
__global__ __launch_bounds__(256) void k_M(const int2* __restrict__ ell, const int* __restrict__ ell_cnt,
                                           const float* __restrict__ Sc, float* __restrict__ Mmat) {
  int b = blockIdx.x & 7;           // batch -> XCD: Sc[b] (2 MB) stays L2-resident
  int n = blockIdx.x >> 3;
  int r = b * NN + n;
  int t = threadIdx.x;
  __shared__ int srk[CAP];
  __shared__ float sav[CAP];
  int cnt = ell_cnt[r];
  size_t base = (size_t)r * CAP;
  for (int e = t; e < cnt; e += 256) {
    int2 p = ell[base + e];
    srk[e] = b * NN + p.x;
    sav[e] = __int_as_float(p.y);
  }
  __syncthreads();
  float a0 = 0.f, a1 = 0.f, a2 = 0.f, a3 = 0.f;     // 4-way MLP on the Sc gathers
  int e = 0;
  for (; e + 4 <= cnt; e += 4) {
    a0 += sav[e + 0] * Sc[(size_t)srk[e + 0] * SELCAP + t];
    a1 += sav[e + 1] * Sc[(size_t)srk[e + 1] * SELCAP + t];
    a2 += sav[e + 2] * Sc[(size_t)srk[e + 2] * SELCAP + t];
    a3 += sav[e + 3] * Sc[(size_t)srk[e + 3] * SELCAP + t];
  }
  for (; e < cnt; ++e) a0 += sav[e] * Sc[(size_t)srk[e] * SELCAP + t];
  Mmat[(size_t)r * SELCAP + t] = (a0 + a1) + (a2 + a3);
}

// ---------- full-grid epilogue: every row of xc and coarse written (no memset needed) ----------
__global__ __launch_bounds__(256) void k_epi2(const float* __restrict__ x, const int2* __restrict__ ell,
                                              const int* __restrict__ ell_cnt, const int2* __restrict__ seldg,
                                              const float* __restrict__ dginv, const int* __restrict__ sel_list,
                                              const int* __restrict__ sel_cnt, const float* __restrict__ Mmat,
                                              float* __restrict__ xc, float* __restrict__ coarse) {
  int b = blockIdx.x & 7;           // batch -> XCD: x[b], Mmat[b] (2 MB each) stay L2-resident
  int m = blockIdx.x >> 3;
  int rm = b * NN + m;
  int t = threadIdx.x;
  __shared__ float row[NN];         // 8 KiB coarse row
  __shared__ int cn[CAP + 1];
  __shared__ float cw[CAP + 1];
  int2 sd_m = seldg[rm];
  bool sel = sd_m.y >= 0;           // block-uniform
  if (!sel) {                       // ~90% of rows: stream zeros, no LDS at all
    f4 z = (f4)(0.f);
    if (t < FD / 4) __builtin_nontemporal_store(z, &((f4*)(xc + (size_t)rm * FD))[t]);
    f4* dco = (f4*)(coarse + (size_t)rm * NN);
    __builtin_nontemporal_store(z, &dco[t]);
    __builtin_nontemporal_store(z, &dco[t + 256]);
    return;
  }
  int nsel = sel_cnt[b]; if (nsel > SELCAP) nsel = SELCAP;
  int cnt = ell_cnt[rm];
#pragma unroll
  for (int j = 0; j < NN / 256; ++j) row[t + j * 256] = 0.f;
  {
    float dgca_m = __int_as_float(sd_m.x);           // dg[m]*cutA[m]
    // column m of S == row m of adj (exact symmetry) plus the diagonal (+1) entry
    for (int j = t; j <= cnt; j += 256) {
      if (j < cnt) {
        int2 e = ell[(size_t)rm * CAP + j];
        cn[j] = b * NN + e.x;
        cw[j] = __int_as_float(e.y) * dgca_m * dginv[b * NN + e.x];  // single gather per entry
      } else {
        cn[j] = rm;
        cw[j] = dgca_m * dginv[rm];
      }
    }
  }
  __syncthreads();
  float axc = 0.f, aco = 0.f;
  for (int e = 0; e <= cnt; ++e) {
    float w = cw[e];
    if (w == 0.f) continue;
    size_t rn = (size_t)cn[e];
    axc += w * x[rn * FD + t];
    aco += w * Mmat[rn * SELCAP + t];
  }
  if (t < nsel) row[sel_list[b * SELCAP + t]] = floorf(aco * 10000.0f) / 10000.0f;
  __builtin_nontemporal_store(axc, &xc[(size_t)rm * FD + t]);
  __syncthreads();
  f4* dst = (f4*)(coarse + (size_t)rm * NN);
  const f4* src = (const f4*)row;
#pragma unroll
  for (int j = 0; j < NN / 4 / 256; ++j)
    __builtin_nontemporal_store(src[t + j * 256], &dst[t + j * 256]);  // stream coarse out
}

extern "C" void kernel_launch(void* const* d_in, const int* in_sizes, int n_in,
                              void* d_out, int out_size, void* d_ws, size_t ws_size,
                              hipStream_t stream) {
  (void)in_sizes; (void)n_in; (void)ws_size; (void)out_size;
  const float* x = (const float*)d_in[0];
  const float* adj = (const float*)d_in[1];
  const float* W = (const float*)d_in[2];
  const float* bptr = (const float*)d_in[3];

  float* out = (float*)d_out;
  const size_t XC_SZ = (size_t)BB * NN * FD;   // 4,194,304
  const size_t CO_SZ = (size_t)BB * NN * NN;   // 33,554,432
  const size_t S_SZ  = (size_t)BB * NN * NN;   // 33,554,432
  float* out_xc = out;
  float* out_co = out + XC_SZ;
  float* out_S  = out + XC_SZ + CO_SZ;
  float* out_ti = out + XC_SZ + CO_SZ + S_SZ;  // topi as float (written fully by k_rank)

  char* w = (char*)d_ws;
  int2*  ell     = (int2*)w;  w += (size_t)BB * NN * CAP * 8;
  float* Sc      = (float*)w; w += (size_t)BB * NN * SELCAP * 4;
  float* Mmat    = (float*)w; w += (size_t)BB * NN * SELCAP * 4;
  int2*  seldg   = (int2*)w;  w += (size_t)BB * NN * 8;
  int*   ell_cnt = (int*)w;   w += (size_t)BB * NN * 4;
  float* dg      = (float*)w; w += (size_t)BB * NN * 4;
  float* dgy     = (float*)w; w += (size_t)BB * NN * 4;
  float* alpha   = (float*)w; w += (size_t)BB * NN * 4;
  float* dginv   = (float*)w; w += (size_t)BB * NN * 4;
  float* cutv    = (float*)w; w += (size_t)BB * 4;
  int*   sel_cnt = (int*)w;   w += (size_t)BB * 4;
  int*   sel_list= (int*)w;   w += (size_t)BB * SELCAP * 4;

  // every output byte written by kernels: xc+coarse by k_epi2, S by k_sbuild, topi by k_rank
  k_spy<<<BB * NN, 256, 0, stream>>>(adj, x, W, ell, ell_cnt, dg, dgy);
  k_alpha<<<BB * NN / 4, 256, 0, stream>>>(ell, ell_cnt, dg, dgy, bptr, alpha);
  k_rank<<<BB * 8, 256, 0, stream>>>(alpha, cutv, out_ti, sel_cnt);
  k_selcut<<<BB * NN / 256, 256, 0, stream>>>(alpha, cutv, dg, seldg, sel_list, sel_cnt);
  k_sbuild<<<BB * NN, 256, 0, stream>>>(ell, ell_cnt, dg, seldg, dginv, Sc, out_S);
  k_M<<<BB * NN, 256, 0, stream>>>(ell, ell_cnt, Sc, Mmat);
  k_epi2<<<BB * NN, 256, 0, stream>>>(x, ell, ell_cnt, seldg, dginv,
                                      sel_list, sel_cnt, Mmat, out_xc, out_co);
}